// Round 3
// baseline (1111.300 us; speedup 1.0000x reference)
//
#include <hip/hip_runtime.h>
#include <hip/hip_bf16.h>

#define NN   30000
#define DIN  128
#define NHD  256      // H*D
#define HH   4
#define DD   64
#define MM   64
#define KK   6
#define EE   480000
#define CCH  32
#define CHUNK 938     // ceil(30000/32)
#define ZOFF 1920000  // 30000*64

__device__ __forceinline__ unsigned f2key(float f) {
    unsigned u = __float_as_uint(f);
    return (u & 0x80000000u) ? ~u : (u | 0x80000000u);
}
__device__ __forceinline__ float key2f(unsigned k) {
    return __uint_as_float((k & 0x80000000u) ? (k ^ 0x80000000u) : ~k);
}

// ---------------------------------------------------------------- init
__global__ void init_kernel(unsigned* gmax) {
    if (threadIdx.x < HH) gmax[threadIdx.x] = 0u;
}

// ---------------------------------------------------------------- K1: qkv GEMM
__device__ __forceinline__ void gemm_one(const float* __restrict__ W,
                                         const float* __restrict__ b,
                                         float* __restrict__ O, float sc,
                                         const float (*zsh)[DIN], float (*wsh)[NHD],
                                         int t, int tx, int ty, int n0) {
    float acc0[16], acc1[16];
    #pragma unroll
    for (int q = 0; q < 16; ++q) { acc0[q] = 0.f; acc1[q] = 0.f; }
    for (int rt = 0; rt < 4; ++rt) {
        __syncthreads();
        #pragma unroll
        for (int q = 0; q < 32; ++q) wsh[q][t] = W[(rt * 32 + q) * NHD + t];
        __syncthreads();
        for (int j = 0; j < 32; ++j) {
            float z0 = zsh[ty][rt * 32 + j];
            float z1 = zsh[ty + 16][rt * 32 + j];
            #pragma unroll
            for (int q = 0; q < 16; ++q) {
                float w = wsh[j][tx * 16 + q];
                acc0[q] += z0 * w;
                acc1[q] += z1 * w;
            }
        }
    }
    int na = n0 + ty, nb = n0 + ty + 16;
    if (na < NN) {
        #pragma unroll
        for (int q = 0; q < 16; q += 4) {
            float4 v;
            v.x = (acc0[q + 0] + b[tx * 16 + q + 0]) * sc;
            v.y = (acc0[q + 1] + b[tx * 16 + q + 1]) * sc;
            v.z = (acc0[q + 2] + b[tx * 16 + q + 2]) * sc;
            v.w = (acc0[q + 3] + b[tx * 16 + q + 3]) * sc;
            *(float4*)&O[na * NHD + tx * 16 + q] = v;
        }
    }
    if (nb < NN) {
        #pragma unroll
        for (int q = 0; q < 16; q += 4) {
            float4 v;
            v.x = (acc1[q + 0] + b[tx * 16 + q + 0]) * sc;
            v.y = (acc1[q + 1] + b[tx * 16 + q + 1]) * sc;
            v.z = (acc1[q + 2] + b[tx * 16 + q + 2]) * sc;
            v.w = (acc1[q + 3] + b[tx * 16 + q + 3]) * sc;
            *(float4*)&O[nb * NHD + tx * 16 + q] = v;
        }
    }
}

__global__ __launch_bounds__(256) void qkv_kernel(
    const float* __restrict__ z,
    const float* __restrict__ Wq, const float* __restrict__ bq,
    const float* __restrict__ Wk, const float* __restrict__ bk,
    const float* __restrict__ Wv, const float* __restrict__ bv,
    float* __restrict__ qb, float* __restrict__ kb, float* __restrict__ vb) {
    __shared__ __align__(16) float zsh[32][DIN];
    __shared__ __align__(16) float wsh[32][NHD];
    const int t = threadIdx.x;
    const int n0 = blockIdx.x * 32;
    #pragma unroll
    for (int q = 0; q < 16; ++q) {
        int idx = t + q * 256;
        int nn = idx >> 7, r = idx & 127;
        int n = n0 + nn;
        zsh[nn][r] = (n < NN) ? z[n * DIN + r] : 0.0f;
    }
    const int tx = t & 15;
    const int ty = t >> 4;
    gemm_one(Wq, bq, qb, 2.0f, zsh, wsh, t, tx, ty, n0);
    gemm_one(Wk, bk, kb, 2.0f, zsh, wsh, t, tx, ty, n0);
    gemm_one(Wv, bv, vb, 1.0f, zsh, wsh, t, tx, ty, n0);
}

// ---------------------------------------------------------------- K2: random features
__device__ __forceinline__ void rf_project(float val, const float* pT, int lane,
                                           float& dd_out, float& s2_out) {
    float dd0 = 0.f, dd1 = 0.f, dd2 = 0.f, dd3 = 0.f;
    float s20 = 0.f, s21 = 0.f;
    #pragma unroll
    for (int d = 0; d < 64; d += 4) {
        float b0 = __shfl(val, d, 64);
        float b1 = __shfl(val, d + 1, 64);
        float b2 = __shfl(val, d + 2, 64);
        float b3 = __shfl(val, d + 3, 64);
        s20 += b0 * b0 + b2 * b2;
        s21 += b1 * b1 + b3 * b3;
        dd0 += b0 * pT[(d + 0) * 65 + lane];
        dd1 += b1 * pT[(d + 1) * 65 + lane];
        dd2 += b2 * pT[(d + 2) * 65 + lane];
        dd3 += b3 * pT[(d + 3) * 65 + lane];
    }
    dd_out = (dd0 + dd1) + (dd2 + dd3);
    s2_out = s20 + s21;
}

__global__ __launch_bounds__(256) void feat_kernel(
    float* __restrict__ qb, float* __restrict__ kb,
    const float* __restrict__ proj, unsigned* __restrict__ gmax) {
    __shared__ float projT[64 * 65];
    const int t = threadIdx.x;
    #pragma unroll
    for (int q = 0; q < 16; ++q) {
        int idx = t + q * 256;
        int m = idx >> 6, d = idx & 63;
        projT[d * 65 + m] = proj[idx];
    }
    __syncthreads();
    const int lane = t & 63;
    const int h = t >> 6;
    const float dn = 0.35355339059327373f;
    float kmax = -3.4e38f;
    const int nbase = blockIdx.x * 64;
    for (int i = 0; i < 64; ++i) {
        int n = nbase + i;
        if (n >= NN) break;
        {   // q: per-row max
            float val = qb[n * NHD + h * DD + lane] * dn;
            float dd, s2;
            rf_project(val, projT, lane, dd, s2);
            float mx = dd;
            #pragma unroll
            for (int off = 32; off; off >>= 1) mx = fmaxf(mx, __shfl_xor(mx, off, 64));
            qb[n * NHD + h * DD + lane] = 0.125f * (__expf(dd - 0.5f * s2 - mx) + 1e-6f);
        }
        {   // k: store dd - diag, track global max(dd)
            float val = kb[n * NHD + h * DD + lane] * dn;
            float dd, s2;
            rf_project(val, projT, lane, dd, s2);
            kmax = fmaxf(kmax, dd);
            kb[n * NHD + h * DD + lane] = dd - 0.5f * s2;
        }
    }
    #pragma unroll
    for (int off = 32; off; off >>= 1) kmax = fmaxf(kmax, __shfl_xor(kmax, off, 64));
    if (lane == 0) atomicMax(&gmax[h], f2key(kmax));
}

// ---------------------------------------------------------------- K3: kp finalize
__global__ void kfin_kernel(float* __restrict__ kb, const unsigned* __restrict__ gmax) {
    int idx = blockIdx.x * 256 + threadIdx.x;  // exactly 7,680,000
    int h = (idx >> 6) & 3;
    float mx = key2f(gmax[h]);
    kb[idx] = 0.125f * (__expf(kb[idx] - mx) + 1e-6f);
}

// ---------------------------------------------------------------- K4: kvs partials
__global__ __launch_bounds__(256) void kvs_kernel(
    const float* __restrict__ kb, const float* __restrict__ vb,
    const float* __restrict__ gum,
    float* __restrict__ kvsp, float* __restrict__ ksp, float* __restrict__ ksump) {
    __shared__ __align__(16) float kp_sh[8 * 64];
    __shared__ __align__(16) float v_sh[8 * 64];
    __shared__ float w_sh[8];
    const int c = blockIdx.x, k = blockIdx.y, h = blockIdx.z;
    const int t = threadIdx.x;
    const int lane = t & 63;   // m
    const int wv = t >> 6;     // d-block
    const int n0 = c * CHUNK;
    const int n1 = (n0 + CHUNK < NN) ? (n0 + CHUNK) : NN;
    float acc[16];
    #pragma unroll
    for (int i = 0; i < 16; ++i) acc[i] = 0.f;
    float ks_acc = 0.f, ksum_acc = 0.f;
    for (int nt = n0; nt < n1; nt += 8) {
        __syncthreads();
        #pragma unroll
        for (int q = 0; q < 4; ++q) {
            int idx = t + q * 256;
            int j = idx >> 7, rem = idx & 127;
            int which = rem >> 6, col = rem & 63;
            int n = nt + j;
            float val = 0.f;
            if (n < n1) val = which ? vb[n * NHD + h * DD + col] : kb[n * NHD + h * DD + col];
            if (which) v_sh[j * 64 + col] = val; else kp_sh[j * 64 + col] = val;
        }
        if (t < 8) {
            int n = nt + t;
            w_sh[t] = (n < n1) ? __expf(gum[n * 24 + h * KK + k] * 4.0f) : 0.f;
        }
        __syncthreads();
        #pragma unroll
        for (int j = 0; j < 8; ++j) {
            float wj = w_sh[j];
            float kpm = kp_sh[j * 64 + lane];
            float a = kpm * wj;
            ks_acc += a;
            ksum_acc += kpm;
            const float4* v4 = (const float4*)&v_sh[j * 64 + wv * 16];
            #pragma unroll
            for (int q = 0; q < 4; ++q) {
                float4 vv = v4[q];
                acc[q * 4 + 0] += a * vv.x;
                acc[q * 4 + 1] += a * vv.y;
                acc[q * 4 + 2] += a * vv.z;
                acc[q * 4 + 3] += a * vv.w;
            }
        }
    }
    int base = (((c * HH + h) * KK + k) * 64 + lane) * 64 + wv * 16;
    float4* o4 = (float4*)&kvsp[base];
    o4[0] = make_float4(acc[0], acc[1], acc[2], acc[3]);
    o4[1] = make_float4(acc[4], acc[5], acc[6], acc[7]);
    o4[2] = make_float4(acc[8], acc[9], acc[10], acc[11]);
    o4[3] = make_float4(acc[12], acc[13], acc[14], acc[15]);
    if (wv == 0) {
        ksp[((c * HH + h) * KK + k) * 64 + lane] = ks_acc;
        if (k == 0) ksump[(c * HH + h) * 64 + lane] = ksum_acc;
    }
}

// ---------------------------------------------------------------- K5: reduce partials
__global__ void reduce_kernel(const float* __restrict__ kvsp, const float* __restrict__ ksp,
                              const float* __restrict__ ksump,
                              float* __restrict__ kvs, float* __restrict__ kss,
                              float* __restrict__ ksum) {
    int idx = blockIdx.x * 256 + threadIdx.x;
    if (idx < 98304) {
        float s = 0.f;
        for (int c = 0; c < CCH; ++c) s += kvsp[c * 98304 + idx];
        kvs[idx] = s;
    } else if (idx < 98304 + 1536) {
        int o = idx - 98304;
        float s = 0.f;
        for (int c = 0; c < CCH; ++c) s += ksp[c * 1536 + o];
        kss[o] = s;
    } else if (idx < 98304 + 1536 + 256) {
        int o = idx - 98304 - 1536;
        float s = 0.f;
        for (int c = 0; c < CCH; ++c) s += ksump[c * 256 + o];
        ksum[o] = s;
    }
}

// ---------------------------------------------------------------- K6: z_num/z_den -> z_out, norm
__global__ __launch_bounds__(256) void znum_kernel(
    const float* __restrict__ qb, const float* __restrict__ kvs,
    const float* __restrict__ kss, const float* __restrict__ ksum,
    float* __restrict__ zout, float* __restrict__ nrm) {
    __shared__ __align__(16) float qpT[64 * 132];   // 8448 floats
    __shared__ float ks_sh[384];
    __shared__ float ksum_sh[64];
    __shared__ float zdi[768];
    const int t = threadIdx.x;
    const int tile = blockIdx.x, h = blockIdx.y;
    const int n0 = tile * 128;
    for (int i = t; i < 384; i += 256) ks_sh[i] = kss[h * 384 + i];
    if (t < 64) ksum_sh[t] = ksum[h * 64 + t];
    #pragma unroll
    for (int q = 0; q < 32; ++q) {
        int idx = t + q * 256;
        int nn2 = idx >> 6, m = idx & 63;
        int n = n0 + nn2;
        qpT[m * 132 + nn2] = (n < NN) ? qb[n * NHD + h * DD + m] : 0.f;
    }
    __syncthreads();
    // z_den (inverse) and norm
    #pragma unroll
    for (int p = 0; p < 4; ++p) {
        int idx = t + p * 256;
        if (idx < 768) {
            int node = idx / 6, k = idx % 6;
            float s = 0.f;
            for (int m = 0; m < 64; ++m) s += qpT[m * 132 + node] * ks_sh[k * 64 + m];
            zdi[idx] = 1.0f / s;
        } else if (idx < 896) {
            int node = idx - 768;
            float s = 0.f;
            for (int m = 0; m < 64; ++m) s += qpT[m * 132 + node] * ksum_sh[m];
            int n = n0 + node;
            if (n < NN) nrm[n * HH + h] = s;
        }
    }
    __syncthreads();
    const int tc = t & 15, tr = t >> 4;
    const float* kvsh = kvs + h * 24576 + tc * 4;
    float out[8][4];
    #pragma unroll
    for (int i = 0; i < 8; ++i) { out[i][0] = 0.f; out[i][1] = 0.f; out[i][2] = 0.f; out[i][3] = 0.f; }
    for (int k = 0; k < KK; ++k) {
        float s[8][4];
        #pragma unroll
        for (int i = 0; i < 8; ++i) { s[i][0] = 0.f; s[i][1] = 0.f; s[i][2] = 0.f; s[i][3] = 0.f; }
        const float* kbase = kvsh + k * 4096;
        #pragma unroll 2
        for (int m = 0; m < 64; ++m) {
            float4 b = *(const float4*)(kbase + m * 64);
            float a[8];
            *(float4*)&a[0] = *(const float4*)&qpT[m * 132 + tr * 8];
            *(float4*)&a[4] = *(const float4*)&qpT[m * 132 + tr * 8 + 4];
            #pragma unroll
            for (int i = 0; i < 8; ++i) {
                s[i][0] += a[i] * b.x;
                s[i][1] += a[i] * b.y;
                s[i][2] += a[i] * b.z;
                s[i][3] += a[i] * b.w;
            }
        }
        #pragma unroll
        for (int i = 0; i < 8; ++i) {
            float zv = zdi[(tr * 8 + i) * 6 + k];
            out[i][0] += s[i][0] * zv;
            out[i][1] += s[i][1] * zv;
            out[i][2] += s[i][2] * zv;
            out[i][3] += s[i][3] * zv;
        }
    }
    const float inv6 = 1.0f / 6.0f;
    #pragma unroll
    for (int i = 0; i < 8; ++i) {
        int n = n0 + tr * 8 + i;
        if (n < NN) {
            float4 o = make_float4(out[i][0] * inv6, out[i][1] * inv6,
                                   out[i][2] * inv6, out[i][3] * inv6);
            *(float4*)&zout[n * NHD + h * DD + tc * 4] = o;
        }
    }
}

// ---------------------------------------------------------------- K7: output projection (f32 out)
__global__ __launch_bounds__(256) void outproj_kernel(
    const float* __restrict__ zout, const float* __restrict__ Wo,
    const float* __restrict__ bo, float* __restrict__ out) {
    __shared__ float zsh[16][NHD];
    const int t = threadIdx.x;
    const int n0 = blockIdx.x * 16;
    #pragma unroll
    for (int q = 0; q < 16; ++q) {
        int idx = t + q * 256;
        int nn2 = idx >> 8, r = idx & 255;
        zsh[nn2][r] = zout[(n0 + nn2) * NHD + r];
    }
    __syncthreads();
    const int c = t & 63, g = t >> 6;
    float acc[4];
    #pragma unroll
    for (int i = 0; i < 4; ++i) acc[i] = bo[c];
    for (int r = 0; r < 256; ++r) {
        float w = Wo[r * 64 + c];
        #pragma unroll
        for (int i = 0; i < 4; ++i) acc[i] += zsh[g + 4 * i][r] * w;
    }
    #pragma unroll
    for (int i = 0; i < 4; ++i)
        out[(n0 + g + 4 * i) * 64 + c] = acc[i];
}

// ---------------------------------------------------------------- K8: edges (f32 out)
__global__ __launch_bounds__(256) void edge_kernel(
    const float* __restrict__ qb, const float* __restrict__ kb,
    const int* __restrict__ ei, const float* __restrict__ nrm,
    float* __restrict__ out) {
    const int t = threadIdx.x;
    const int lane = t & 63, w = t >> 6;
    const int e = blockIdx.x * 4 + w;  // grid sized exactly
    const int s = ei[e], d = ei[EE + e];
    float4 qv = *(const float4*)&qb[d * NHD + lane * 4];
    float4 kv = *(const float4*)&kb[s * NHD + lane * 4];
    float p = qv.x * kv.x + qv.y * kv.y + qv.z * kv.z + qv.w * kv.w;
    #pragma unroll
    for (int off = 1; off < 16; off <<= 1) p += __shfl_xor(p, off, 64);
    if ((lane & 15) == 0) {
        int h = lane >> 4;
        out[ZOFF + e * 4 + h] = p / nrm[d * HH + h];
    }
}

// ---------------------------------------------------------------- launch
extern "C" void kernel_launch(void* const* d_in, const int* in_sizes, int n_in,
                              void* d_out, int out_size, void* d_ws, size_t ws_size,
                              hipStream_t stream) {
    (void)in_sizes; (void)n_in; (void)out_size;
    const float* z  = (const float*)d_in[0];
    const float* Wq = (const float*)d_in[1];
    const float* bq = (const float*)d_in[2];
    const float* Wk = (const float*)d_in[3];
    const float* bk = (const float*)d_in[4];
    const float* Wv = (const float*)d_in[5];
    const float* bv = (const float*)d_in[6];
    const float* Wo = (const float*)d_in[7];
    const float* bo = (const float*)d_in[8];
    const float* proj = (const float*)d_in[9];
    const float* gum  = (const float*)d_in[10];
    const int*   ei   = (const int*)d_in[11];
    float* out = (float*)d_out;
    float* ws = (float*)d_ws;

    const size_t WS_NEEDED = (size_t)26463172 * 4;
    if (ws_size < WS_NEEDED) return;  // scratch too small: fail cleanly

    float* qb    = ws;                  // 7,680,000
    float* kb    = ws + 7680000;        // 7,680,000
    float* vb    = ws + 15360000;       // 7,680,000 (reused as zout after kvs)
    float* zout  = vb;
    float* kvsp  = ws + 23040000;       // 3,145,728
    float* ksp   = ws + 26185728;       // 49,152
    float* ksump = ws + 26234880;       // 8,192
    float* kvs   = ws + 26243072;       // 98,304
    float* kss   = ws + 26341376;       // 1,536
    float* ksum  = ws + 26342912;       // 256
    float* nrm   = ws + 26343168;       // 120,000
    unsigned* gmax = (unsigned*)(ws + 26463168);  // 4

    init_kernel<<<1, 64, 0, stream>>>(gmax);
    qkv_kernel<<<938, 256, 0, stream>>>(z, Wq, bq, Wk, bk, Wv, bv, qb, kb, vb);
    feat_kernel<<<469, 256, 0, stream>>>(qb, kb, proj, gmax);
    kfin_kernel<<<30000, 256, 0, stream>>>(kb, gmax);
    kvs_kernel<<<dim3(CCH, KK, HH), 256, 0, stream>>>(kb, vb, gum, kvsp, ksp, ksump);
    reduce_kernel<<<392, 256, 0, stream>>>(kvsp, ksp, ksump, kvs, kss, ksum);
    znum_kernel<<<dim3(235, HH), 256, 0, stream>>>(qb, kvs, kss, ksum, zout, nrm);
    outproj_kernel<<<1875, 256, 0, stream>>>(zout, Wo, bo, out);
    edge_kernel<<<120000, 256, 0, stream>>>(qb, kb, ei, nrm, out);
}

// Round 4
// 960.573 us; speedup vs baseline: 1.1569x; 1.1569x over previous
//
#include <hip/hip_runtime.h>
#include <hip/hip_bf16.h>

#define NN   30000
#define DIN  128
#define NHD  256      // H*D
#define HH   4
#define DD   64
#define MM   64
#define KK   6
#define EE   480000
#define CCH  32
#define CHUNK 938     // ceil(30000/32)
#define ZOFF 1920000  // 30000*64

__device__ __forceinline__ unsigned f2key(float f) {
    unsigned u = __float_as_uint(f);
    return (u & 0x80000000u) ? ~u : (u | 0x80000000u);
}
__device__ __forceinline__ float key2f(unsigned k) {
    return __uint_as_float((k & 0x80000000u) ? (k ^ 0x80000000u) : ~k);
}

// ---------------------------------------------------------------- init
__global__ void init_kernel(unsigned* gmax) {
    if (threadIdx.x < HH) gmax[threadIdx.x] = 0u;
}

// ---------------------------------------------------------------- K1: qkv GEMM
__device__ __forceinline__ void gemm_one(const float* __restrict__ W,
                                         const float* __restrict__ b,
                                         float* __restrict__ O, float sc,
                                         const float (*zsh)[DIN], float (*wsh)[NHD],
                                         int t, int tx, int ty, int n0) {
    float acc0[16], acc1[16];
    #pragma unroll
    for (int q = 0; q < 16; ++q) { acc0[q] = 0.f; acc1[q] = 0.f; }
    for (int rt = 0; rt < 4; ++rt) {
        __syncthreads();
        #pragma unroll
        for (int q = 0; q < 32; ++q) wsh[q][t] = W[(rt * 32 + q) * NHD + t];
        __syncthreads();
        for (int j = 0; j < 32; ++j) {
            float z0 = zsh[ty][rt * 32 + j];
            float z1 = zsh[ty + 16][rt * 32 + j];
            #pragma unroll
            for (int q = 0; q < 16; ++q) {
                float w = wsh[j][tx * 16 + q];
                acc0[q] += z0 * w;
                acc1[q] += z1 * w;
            }
        }
    }
    int na = n0 + ty, nb = n0 + ty + 16;
    if (na < NN) {
        #pragma unroll
        for (int q = 0; q < 16; q += 4) {
            float4 v;
            v.x = (acc0[q + 0] + b[tx * 16 + q + 0]) * sc;
            v.y = (acc0[q + 1] + b[tx * 16 + q + 1]) * sc;
            v.z = (acc0[q + 2] + b[tx * 16 + q + 2]) * sc;
            v.w = (acc0[q + 3] + b[tx * 16 + q + 3]) * sc;
            *(float4*)&O[na * NHD + tx * 16 + q] = v;
        }
    }
    if (nb < NN) {
        #pragma unroll
        for (int q = 0; q < 16; q += 4) {
            float4 v;
            v.x = (acc1[q + 0] + b[tx * 16 + q + 0]) * sc;
            v.y = (acc1[q + 1] + b[tx * 16 + q + 1]) * sc;
            v.z = (acc1[q + 2] + b[tx * 16 + q + 2]) * sc;
            v.w = (acc1[q + 3] + b[tx * 16 + q + 3]) * sc;
            *(float4*)&O[nb * NHD + tx * 16 + q] = v;
        }
    }
}

__global__ __launch_bounds__(256) void qkv_kernel(
    const float* __restrict__ z,
    const float* __restrict__ Wq, const float* __restrict__ bq,
    const float* __restrict__ Wk, const float* __restrict__ bk,
    const float* __restrict__ Wv, const float* __restrict__ bv,
    float* __restrict__ qb, float* __restrict__ kb, float* __restrict__ vb) {
    __shared__ __align__(16) float zsh[32][DIN];
    __shared__ __align__(16) float wsh[32][NHD];
    const int t = threadIdx.x;
    const int n0 = blockIdx.x * 32;
    #pragma unroll
    for (int q = 0; q < 16; ++q) {
        int idx = t + q * 256;
        int nn = idx >> 7, r = idx & 127;
        int n = n0 + nn;
        zsh[nn][r] = (n < NN) ? z[n * DIN + r] : 0.0f;
    }
    const int tx = t & 15;
    const int ty = t >> 4;
    gemm_one(Wq, bq, qb, 2.0f, zsh, wsh, t, tx, ty, n0);
    gemm_one(Wk, bk, kb, 2.0f, zsh, wsh, t, tx, ty, n0);
    gemm_one(Wv, bv, vb, 1.0f, zsh, wsh, t, tx, ty, n0);
}

// ---------------------------------------------------------------- K2: random features
__device__ __forceinline__ void rf_project(float val, const float* pT, int lane,
                                           float& dd_out, float& s2_out) {
    float dd0 = 0.f, dd1 = 0.f, dd2 = 0.f, dd3 = 0.f;
    float s20 = 0.f, s21 = 0.f;
    #pragma unroll
    for (int d = 0; d < 64; d += 4) {
        float b0 = __shfl(val, d, 64);
        float b1 = __shfl(val, d + 1, 64);
        float b2 = __shfl(val, d + 2, 64);
        float b3 = __shfl(val, d + 3, 64);
        s20 += b0 * b0 + b2 * b2;
        s21 += b1 * b1 + b3 * b3;
        dd0 += b0 * pT[(d + 0) * 65 + lane];
        dd1 += b1 * pT[(d + 1) * 65 + lane];
        dd2 += b2 * pT[(d + 2) * 65 + lane];
        dd3 += b3 * pT[(d + 3) * 65 + lane];
    }
    dd_out = (dd0 + dd1) + (dd2 + dd3);
    s2_out = s20 + s21;
}

__global__ __launch_bounds__(256) void feat_kernel(
    float* __restrict__ qb, float* __restrict__ kb,
    const float* __restrict__ proj, unsigned* __restrict__ gmax) {
    __shared__ float projT[64 * 65];
    const int t = threadIdx.x;
    #pragma unroll
    for (int q = 0; q < 16; ++q) {
        int idx = t + q * 256;
        int m = idx >> 6, d = idx & 63;
        projT[d * 65 + m] = proj[idx];
    }
    __syncthreads();
    const int lane = t & 63;
    const int h = t >> 6;
    const float dn = 0.35355339059327373f;
    float kmax = -3.4e38f;
    const int nbase = blockIdx.x * 64;
    for (int i = 0; i < 64; ++i) {
        int n = nbase + i;
        if (n >= NN) break;
        {   // q: per-row max
            float val = qb[n * NHD + h * DD + lane] * dn;
            float dd, s2;
            rf_project(val, projT, lane, dd, s2);
            float mx = dd;
            #pragma unroll
            for (int off = 32; off; off >>= 1) mx = fmaxf(mx, __shfl_xor(mx, off, 64));
            qb[n * NHD + h * DD + lane] = 0.125f * (__expf(dd - 0.5f * s2 - mx) + 1e-6f);
        }
        {   // k: store dd - diag, track global max(dd)
            float val = kb[n * NHD + h * DD + lane] * dn;
            float dd, s2;
            rf_project(val, projT, lane, dd, s2);
            kmax = fmaxf(kmax, dd);
            kb[n * NHD + h * DD + lane] = dd - 0.5f * s2;
        }
    }
    #pragma unroll
    for (int off = 32; off; off >>= 1) kmax = fmaxf(kmax, __shfl_xor(kmax, off, 64));
    if (lane == 0) atomicMax(&gmax[h], f2key(kmax));
}

// ---------------------------------------------------------------- K3: kp finalize
__global__ void kfin_kernel(float* __restrict__ kb, const unsigned* __restrict__ gmax) {
    int idx = blockIdx.x * 256 + threadIdx.x;  // exactly 7,680,000
    int h = (idx >> 6) & 3;
    float mx = key2f(gmax[h]);
    kb[idx] = 0.125f * (__expf(kb[idx] - mx) + 1e-6f);
}

// ---------------------------------------------------------------- K4: kvs partials (2 k per block)
__global__ __launch_bounds__(256) void kvs_kernel(
    const float* __restrict__ kb, const float* __restrict__ vb,
    const float* __restrict__ gum,
    float* __restrict__ kvsp, float* __restrict__ ksp, float* __restrict__ ksump) {
    __shared__ __align__(16) float kp_sh[8 * 64];
    __shared__ __align__(16) float v_sh[8 * 64];
    __shared__ float w_sh[16];
    const int c = blockIdx.x, kg = blockIdx.y, h = blockIdx.z;
    const int k0 = kg * 2;
    const int t = threadIdx.x;
    const int lane = t & 63;   // m
    const int wv = t >> 6;     // d-block
    const int n0 = c * CHUNK;
    const int n1 = (n0 + CHUNK < NN) ? (n0 + CHUNK) : NN;
    float acc[2][16];
    #pragma unroll
    for (int kk = 0; kk < 2; ++kk)
        #pragma unroll
        for (int i = 0; i < 16; ++i) acc[kk][i] = 0.f;
    float ks_acc[2] = {0.f, 0.f};
    float ksum_acc = 0.f;
    for (int nt = n0; nt < n1; nt += 8) {
        __syncthreads();
        #pragma unroll
        for (int q = 0; q < 4; ++q) {
            int idx = t + q * 256;
            int j = idx >> 7, rem = idx & 127;
            int which = rem >> 6, col = rem & 63;
            int n = nt + j;
            float val = 0.f;
            if (n < n1) val = which ? vb[n * NHD + h * DD + col] : kb[n * NHD + h * DD + col];
            if (which) v_sh[j * 64 + col] = val; else kp_sh[j * 64 + col] = val;
        }
        if (t < 16) {
            int j = t & 7, kk = t >> 3;
            int n = nt + j;
            w_sh[t] = (n < n1) ? __expf(gum[n * 24 + h * KK + k0 + kk] * 4.0f) : 0.f;
        }
        __syncthreads();
        #pragma unroll
        for (int j = 0; j < 8; ++j) {
            float kpm = kp_sh[j * 64 + lane];
            ksum_acc += kpm;
            const float4* v4 = (const float4*)&v_sh[j * 64 + wv * 16];
            float4 vv0 = v4[0], vv1 = v4[1], vv2 = v4[2], vv3 = v4[3];
            #pragma unroll
            for (int kk = 0; kk < 2; ++kk) {
                float a = kpm * w_sh[kk * 8 + j];
                ks_acc[kk] += a;
                acc[kk][ 0] += a * vv0.x; acc[kk][ 1] += a * vv0.y;
                acc[kk][ 2] += a * vv0.z; acc[kk][ 3] += a * vv0.w;
                acc[kk][ 4] += a * vv1.x; acc[kk][ 5] += a * vv1.y;
                acc[kk][ 6] += a * vv1.z; acc[kk][ 7] += a * vv1.w;
                acc[kk][ 8] += a * vv2.x; acc[kk][ 9] += a * vv2.y;
                acc[kk][10] += a * vv2.z; acc[kk][11] += a * vv2.w;
                acc[kk][12] += a * vv3.x; acc[kk][13] += a * vv3.y;
                acc[kk][14] += a * vv3.z; acc[kk][15] += a * vv3.w;
            }
        }
    }
    #pragma unroll
    for (int kk = 0; kk < 2; ++kk) {
        int base = (((c * HH + h) * KK + k0 + kk) * 64 + lane) * 64 + wv * 16;
        float4* o4 = (float4*)&kvsp[base];
        o4[0] = make_float4(acc[kk][0], acc[kk][1], acc[kk][2], acc[kk][3]);
        o4[1] = make_float4(acc[kk][4], acc[kk][5], acc[kk][6], acc[kk][7]);
        o4[2] = make_float4(acc[kk][8], acc[kk][9], acc[kk][10], acc[kk][11]);
        o4[3] = make_float4(acc[kk][12], acc[kk][13], acc[kk][14], acc[kk][15]);
    }
    if (wv == 0) {
        ksp[((c * HH + h) * KK + k0 + 0) * 64 + lane] = ks_acc[0];
        ksp[((c * HH + h) * KK + k0 + 1) * 64 + lane] = ks_acc[1];
        if (kg == 0) ksump[(c * HH + h) * 64 + lane] = ksum_acc;
    }
}

// ---------------------------------------------------------------- K5: reduce partials
__global__ void reduce_kernel(const float* __restrict__ kvsp, const float* __restrict__ ksp,
                              const float* __restrict__ ksump,
                              float* __restrict__ kvs, float* __restrict__ kss,
                              float* __restrict__ ksum) {
    int idx = blockIdx.x * 256 + threadIdx.x;
    if (idx < 98304) {
        float s = 0.f;
        for (int c = 0; c < CCH; ++c) s += kvsp[c * 98304 + idx];
        kvs[idx] = s;
    } else if (idx < 98304 + 1536) {
        int o = idx - 98304;
        float s = 0.f;
        for (int c = 0; c < CCH; ++c) s += ksp[c * 1536 + o];
        kss[o] = s;
    } else if (idx < 98304 + 1536 + 256) {
        int o = idx - 98304 - 1536;
        float s = 0.f;
        for (int c = 0; c < CCH; ++c) s += ksump[c * 256 + o];
        ksum[o] = s;
    }
}

// ---------------------------------------------------------------- K6: z_num/z_den -> z_out, norm
// LDS plan (floats): [0,4096) kvs tile (phase2) aliases ks_sh[0,384)+ksum_sh[384,448) (phase1);
// [4096,12544) qpT (stride 132); [12544,13312) zdi.  Total 53,248 B -> 3 blocks/CU.
__global__ __launch_bounds__(256) void znum_kernel(
    const float* __restrict__ qb, const float* __restrict__ kvs,
    const float* __restrict__ kss, const float* __restrict__ ksum,
    float* __restrict__ zout, float* __restrict__ nrm) {
    __shared__ __align__(16) float smem[13312];
    float* kvs_sh  = smem;          // 4096 (phase 2)
    float* ks_sh   = smem;          // 384  (phase 1 only)
    float* ksum_sh = smem + 384;    // 64   (phase 1 only)
    float* qpT     = smem + 4096;   // 8448
    float* zdi     = smem + 12544;  // 768
    const int t = threadIdx.x;
    const int tile = blockIdx.x, h = blockIdx.y;
    const int n0 = tile * 128;
    for (int i = t; i < 384; i += 256) ks_sh[i] = kss[h * 384 + i];
    if (t < 64) ksum_sh[t] = ksum[h * 64 + t];
    #pragma unroll
    for (int q = 0; q < 32; ++q) {
        int idx = t + q * 256;
        int nn2 = idx >> 6, m = idx & 63;
        int n = n0 + nn2;
        qpT[m * 132 + nn2] = (n < NN) ? qb[n * NHD + h * DD + m] : 0.f;
    }
    __syncthreads();
    // z_den (inverse) and norm
    #pragma unroll
    for (int p = 0; p < 4; ++p) {
        int idx = t + p * 256;
        if (idx < 768) {
            int node = idx / 6, k = idx % 6;
            float s = 0.f;
            for (int m = 0; m < 64; ++m) s += qpT[m * 132 + node] * ks_sh[k * 64 + m];
            zdi[idx] = 1.0f / s;
        } else if (idx < 896) {
            int node = idx - 768;
            float s = 0.f;
            for (int m = 0; m < 64; ++m) s += qpT[m * 132 + node] * ksum_sh[m];
            int n = n0 + node;
            if (n < NN) nrm[n * HH + h] = s;
        }
    }
    __syncthreads();   // phase-1 reads of ks_sh/ksum_sh complete before kvs_sh overwrite
    const int tc = t & 15, tr = t >> 4;
    float out[8][4];
    #pragma unroll
    for (int i = 0; i < 8; ++i) { out[i][0] = 0.f; out[i][1] = 0.f; out[i][2] = 0.f; out[i][3] = 0.f; }
    for (int k = 0; k < KK; ++k) {
        const float* src = kvs + h * 24576 + k * 4096;
        #pragma unroll
        for (int q = 0; q < 16; ++q) kvs_sh[t + q * 256] = src[t + q * 256];
        __syncthreads();
        float s[8][4];
        #pragma unroll
        for (int i = 0; i < 8; ++i) { s[i][0] = 0.f; s[i][1] = 0.f; s[i][2] = 0.f; s[i][3] = 0.f; }
        const float* kbase = kvs_sh + tc * 4;
        #pragma unroll 4
        for (int m = 0; m < 64; ++m) {
            float4 b = *(const float4*)(kbase + m * 64);
            float a[8];
            *(float4*)&a[0] = *(const float4*)&qpT[m * 132 + tr * 8];
            *(float4*)&a[4] = *(const float4*)&qpT[m * 132 + tr * 8 + 4];
            #pragma unroll
            for (int i = 0; i < 8; ++i) {
                s[i][0] += a[i] * b.x;
                s[i][1] += a[i] * b.y;
                s[i][2] += a[i] * b.z;
                s[i][3] += a[i] * b.w;
            }
        }
        #pragma unroll
        for (int i = 0; i < 8; ++i) {
            float zv = zdi[(tr * 8 + i) * 6 + k];
            out[i][0] += s[i][0] * zv;
            out[i][1] += s[i][1] * zv;
            out[i][2] += s[i][2] * zv;
            out[i][3] += s[i][3] * zv;
        }
        __syncthreads();   // all reads of kvs_sh done before next k's overwrite
    }
    const float inv6 = 1.0f / 6.0f;
    #pragma unroll
    for (int i = 0; i < 8; ++i) {
        int n = n0 + tr * 8 + i;
        if (n < NN) {
            float4 o = make_float4(out[i][0] * inv6, out[i][1] * inv6,
                                   out[i][2] * inv6, out[i][3] * inv6);
            *(float4*)&zout[n * NHD + h * DD + tc * 4] = o;
        }
    }
}

// ---------------------------------------------------------------- K7: output projection (f32 out)
__global__ __launch_bounds__(256) void outproj_kernel(
    const float* __restrict__ zout, const float* __restrict__ Wo,
    const float* __restrict__ bo, float* __restrict__ out) {
    __shared__ float zsh[16][NHD];
    const int t = threadIdx.x;
    const int n0 = blockIdx.x * 16;
    #pragma unroll
    for (int q = 0; q < 16; ++q) {
        int idx = t + q * 256;
        int nn2 = idx >> 8, r = idx & 255;
        zsh[nn2][r] = zout[(n0 + nn2) * NHD + r];
    }
    __syncthreads();
    const int c = t & 63, g = t >> 6;
    float acc[4];
    #pragma unroll
    for (int i = 0; i < 4; ++i) acc[i] = bo[c];
    for (int r = 0; r < 256; ++r) {
        float w = Wo[r * 64 + c];
        #pragma unroll
        for (int i = 0; i < 4; ++i) acc[i] += zsh[g + 4 * i][r] * w;
    }
    #pragma unroll
    for (int i = 0; i < 4; ++i)
        out[(n0 + g + 4 * i) * 64 + c] = acc[i];
}

// ---------------------------------------------------------------- K8: edges (f32 out)
__global__ __launch_bounds__(256) void edge_kernel(
    const float* __restrict__ qb, const float* __restrict__ kb,
    const int* __restrict__ ei, const float* __restrict__ nrm,
    float* __restrict__ out) {
    const int t = threadIdx.x;
    const int lane = t & 63, w = t >> 6;
    const int e = blockIdx.x * 4 + w;  // grid sized exactly
    const int s = ei[e], d = ei[EE + e];
    float4 qv = *(const float4*)&qb[d * NHD + lane * 4];
    float4 kv = *(const float4*)&kb[s * NHD + lane * 4];
    float p = qv.x * kv.x + qv.y * kv.y + qv.z * kv.z + qv.w * kv.w;
    #pragma unroll
    for (int off = 1; off < 16; off <<= 1) p += __shfl_xor(p, off, 64);
    if ((lane & 15) == 0) {
        int h = lane >> 4;
        out[ZOFF + e * 4 + h] = p / nrm[d * HH + h];
    }
}

// ---------------------------------------------------------------- launch
extern "C" void kernel_launch(void* const* d_in, const int* in_sizes, int n_in,
                              void* d_out, int out_size, void* d_ws, size_t ws_size,
                              hipStream_t stream) {
    (void)in_sizes; (void)n_in; (void)out_size;
    const float* z  = (const float*)d_in[0];
    const float* Wq = (const float*)d_in[1];
    const float* bq = (const float*)d_in[2];
    const float* Wk = (const float*)d_in[3];
    const float* bk = (const float*)d_in[4];
    const float* Wv = (const float*)d_in[5];
    const float* bv = (const float*)d_in[6];
    const float* Wo = (const float*)d_in[7];
    const float* bo = (const float*)d_in[8];
    const float* proj = (const float*)d_in[9];
    const float* gum  = (const float*)d_in[10];
    const int*   ei   = (const int*)d_in[11];
    float* out = (float*)d_out;
    float* ws = (float*)d_ws;

    const size_t WS_NEEDED = (size_t)26463172 * 4;
    if (ws_size < WS_NEEDED) return;  // scratch too small: fail cleanly

    float* qb    = ws;                  // 7,680,000
    float* kb    = ws + 7680000;        // 7,680,000
    float* vb    = ws + 15360000;       // 7,680,000 (reused as zout after kvs)
    float* zout  = vb;
    float* kvsp  = ws + 23040000;       // 3,145,728
    float* ksp   = ws + 26185728;       // 49,152
    float* ksump = ws + 26234880;       // 8,192
    float* kvs   = ws + 26243072;       // 98,304
    float* kss   = ws + 26341376;       // 1,536
    float* ksum  = ws + 26342912;       // 256
    float* nrm   = ws + 26343168;       // 120,000
    unsigned* gmax = (unsigned*)(ws + 26463168);  // 4

    init_kernel<<<1, 64, 0, stream>>>(gmax);
    qkv_kernel<<<938, 256, 0, stream>>>(z, Wq, bq, Wk, bk, Wv, bv, qb, kb, vb);
    feat_kernel<<<469, 256, 0, stream>>>(qb, kb, proj, gmax);
    kfin_kernel<<<30000, 256, 0, stream>>>(kb, gmax);
    kvs_kernel<<<dim3(CCH, 3, HH), 256, 0, stream>>>(kb, vb, gum, kvsp, ksp, ksump);
    reduce_kernel<<<392, 256, 0, stream>>>(kvsp, ksp, ksump, kvs, kss, ksum);
    znum_kernel<<<dim3(235, HH), 256, 0, stream>>>(qb, kvs, kss, ksum, zout, nrm);
    outproj_kernel<<<1875, 256, 0, stream>>>(zout, Wo, bo, out);
    edge_kernel<<<120000, 256, 0, stream>>>(qb, kb, ei, nrm, out);
}

// Round 5
// 637.599 us; speedup vs baseline: 1.7429x; 1.5065x over previous
//
#include <hip/hip_runtime.h>
#include <hip/hip_bf16.h>

#define NN   30000
#define DIN  128
#define NHD  256      // H*D
#define HH   4
#define DD   64
#define MM   64
#define KK   6
#define EE   480000
#define ZOFF 1920000  // 30000*64

__device__ __forceinline__ unsigned f2key(float f) {
    unsigned u = __float_as_uint(f);
    return (u & 0x80000000u) ? ~u : (u | 0x80000000u);
}
__device__ __forceinline__ float key2f(unsigned k) {
    return __uint_as_float((k & 0x80000000u) ? (k ^ 0x80000000u) : ~k);
}

// ---------------------------------------------------------------- init
__global__ void init_kernel(unsigned* gmax) {
    if (threadIdx.x < HH) gmax[threadIdx.x] = 0u;
}

// ---------------------------------------------------------------- K1: qkv GEMM
__device__ __forceinline__ void gemm_one(const float* __restrict__ W,
                                         const float* __restrict__ b,
                                         float* __restrict__ O, float sc,
                                         const float (*zsh)[DIN], float (*wsh)[NHD],
                                         int t, int tx, int ty, int n0) {
    float acc0[16], acc1[16];
    #pragma unroll
    for (int q = 0; q < 16; ++q) { acc0[q] = 0.f; acc1[q] = 0.f; }
    for (int rt = 0; rt < 4; ++rt) {
        __syncthreads();
        #pragma unroll
        for (int q = 0; q < 32; ++q) wsh[q][t] = W[(rt * 32 + q) * NHD + t];
        __syncthreads();
        for (int j = 0; j < 32; ++j) {
            float z0 = zsh[ty][rt * 32 + j];
            float z1 = zsh[ty + 16][rt * 32 + j];
            #pragma unroll
            for (int q = 0; q < 16; ++q) {
                float w = wsh[j][tx * 16 + q];
                acc0[q] += z0 * w;
                acc1[q] += z1 * w;
            }
        }
    }
    int na = n0 + ty, nb = n0 + ty + 16;
    if (na < NN) {
        #pragma unroll
        for (int q = 0; q < 16; q += 4) {
            float4 v;
            v.x = (acc0[q + 0] + b[tx * 16 + q + 0]) * sc;
            v.y = (acc0[q + 1] + b[tx * 16 + q + 1]) * sc;
            v.z = (acc0[q + 2] + b[tx * 16 + q + 2]) * sc;
            v.w = (acc0[q + 3] + b[tx * 16 + q + 3]) * sc;
            *(float4*)&O[na * NHD + tx * 16 + q] = v;
        }
    }
    if (nb < NN) {
        #pragma unroll
        for (int q = 0; q < 16; q += 4) {
            float4 v;
            v.x = (acc1[q + 0] + b[tx * 16 + q + 0]) * sc;
            v.y = (acc1[q + 1] + b[tx * 16 + q + 1]) * sc;
            v.z = (acc1[q + 2] + b[tx * 16 + q + 2]) * sc;
            v.w = (acc1[q + 3] + b[tx * 16 + q + 3]) * sc;
            *(float4*)&O[nb * NHD + tx * 16 + q] = v;
        }
    }
}

__global__ __launch_bounds__(256) void qkv_kernel(
    const float* __restrict__ z,
    const float* __restrict__ Wq, const float* __restrict__ bq,
    const float* __restrict__ Wk, const float* __restrict__ bk,
    const float* __restrict__ Wv, const float* __restrict__ bv,
    float* __restrict__ qb, float* __restrict__ kb, float* __restrict__ vb) {
    __shared__ __align__(16) float zsh[32][DIN];
    __shared__ __align__(16) float wsh[32][NHD];
    const int t = threadIdx.x;
    const int n0 = blockIdx.x * 32;
    #pragma unroll
    for (int q = 0; q < 16; ++q) {
        int idx = t + q * 256;
        int nn = idx >> 7, r = idx & 127;
        int n = n0 + nn;
        zsh[nn][r] = (n < NN) ? z[n * DIN + r] : 0.0f;
    }
    const int tx = t & 15;
    const int ty = t >> 4;
    gemm_one(Wq, bq, qb, 2.0f, zsh, wsh, t, tx, ty, n0);
    gemm_one(Wk, bk, kb, 2.0f, zsh, wsh, t, tx, ty, n0);
    gemm_one(Wv, bv, vb, 1.0f, zsh, wsh, t, tx, ty, n0);
}

// ---------------------------------------------------------------- K2: random features (GEMM form)
// block = 64 nodes x 1 head; dd = tile(64x64) @ projT; both staged transposed in LDS.
__global__ __launch_bounds__(256) void feat_kernel(
    float* __restrict__ qb, float* __restrict__ kb,
    const float* __restrict__ proj, unsigned* __restrict__ gmax) {
    __shared__ __align__(16) float pT[64][68];   // pT[d][m]
    __shared__ __align__(16) float tT[64][68];   // tT[d][n]
    __shared__ float diag_sh[64];
    __shared__ float wmax_sh[4];
    const int t = threadIdx.x;
    const int h = blockIdx.y;
    const int n0 = blockIdx.x * 64;
    const int tx = t & 15, ty = t >> 4;
    const float dn = 0.35355339059327373f;  // 64^-0.25
    const float4* proj4 = (const float4*)proj;
    #pragma unroll
    for (int q = 0; q < 4; ++q) {
        int idx4 = t + q * 256;
        int m = idx4 >> 4, d4 = idx4 & 15;
        float4 v = proj4[m * 16 + d4];
        pT[d4 * 4 + 0][m] = v.x; pT[d4 * 4 + 1][m] = v.y;
        pT[d4 * 4 + 2][m] = v.z; pT[d4 * 4 + 3][m] = v.w;
    }
    #pragma unroll
    for (int pass = 0; pass < 2; ++pass) {
        float* buf = pass ? kb : qb;
        const float4* b4 = (const float4*)buf;
        __syncthreads();
        #pragma unroll
        for (int q = 0; q < 4; ++q) {
            int idx4 = t + q * 256;
            int n = idx4 >> 4, d4 = idx4 & 15;
            float4 v = make_float4(0.f, 0.f, 0.f, 0.f);
            if (n0 + n < NN) v = b4[(n0 + n) * 64 + h * 16 + d4];
            tT[d4 * 4 + 0][n] = v.x * dn; tT[d4 * 4 + 1][n] = v.y * dn;
            tT[d4 * 4 + 2][n] = v.z * dn; tT[d4 * 4 + 3][n] = v.w * dn;
        }
        __syncthreads();
        if (t < 64) {
            float s = 0.f;
            #pragma unroll 8
            for (int d = 0; d < 64; ++d) { float v = tT[d][t]; s += v * v; }
            diag_sh[t] = 0.5f * s;
        }
        __syncthreads();
        float acc[4][4];
        #pragma unroll
        for (int i = 0; i < 4; ++i)
            #pragma unroll
            for (int j = 0; j < 4; ++j) acc[i][j] = 0.f;
        #pragma unroll 8
        for (int d = 0; d < 64; ++d) {
            float4 a = *(const float4*)&tT[d][ty * 4];
            float4 b = *(const float4*)&pT[d][tx * 4];
            float a_[4] = {a.x, a.y, a.z, a.w};
            float b_[4] = {b.x, b.y, b.z, b.w};
            #pragma unroll
            for (int i = 0; i < 4; ++i)
                #pragma unroll
                for (int j = 0; j < 4; ++j) acc[i][j] += a_[i] * b_[j];
        }
        if (pass == 0) {
            #pragma unroll
            for (int i = 0; i < 4; ++i) {
                int n = n0 + ty * 4 + i;
                float mx = fmaxf(fmaxf(acc[i][0], acc[i][1]), fmaxf(acc[i][2], acc[i][3]));
                mx = fmaxf(mx, __shfl_xor(mx, 1, 64));
                mx = fmaxf(mx, __shfl_xor(mx, 2, 64));
                mx = fmaxf(mx, __shfl_xor(mx, 4, 64));
                mx = fmaxf(mx, __shfl_xor(mx, 8, 64));
                if (n < NN) {
                    float dg = diag_sh[ty * 4 + i] + mx;
                    float4 o;
                    o.x = 0.125f * (__expf(acc[i][0] - dg) + 1e-6f);
                    o.y = 0.125f * (__expf(acc[i][1] - dg) + 1e-6f);
                    o.z = 0.125f * (__expf(acc[i][2] - dg) + 1e-6f);
                    o.w = 0.125f * (__expf(acc[i][3] - dg) + 1e-6f);
                    *(float4*)&qb[n * NHD + h * DD + tx * 4] = o;
                }
            }
        } else {
            float km = -3.4e38f;
            #pragma unroll
            for (int i = 0; i < 4; ++i) {
                int n = n0 + ty * 4 + i;
                if (n < NN) {
                    float dg = diag_sh[ty * 4 + i];
                    float4 o;
                    o.x = acc[i][0] - dg; o.y = acc[i][1] - dg;
                    o.z = acc[i][2] - dg; o.w = acc[i][3] - dg;
                    *(float4*)&kb[n * NHD + h * DD + tx * 4] = o;
                    km = fmaxf(km, fmaxf(fmaxf(acc[i][0], acc[i][1]),
                                         fmaxf(acc[i][2], acc[i][3])));
                }
            }
            #pragma unroll
            for (int off = 1; off < 64; off <<= 1) km = fmaxf(km, __shfl_xor(km, off, 64));
            if ((t & 63) == 0) wmax_sh[t >> 6] = km;
            __syncthreads();
            if (t == 0) {
                float m2 = fmaxf(fmaxf(wmax_sh[0], wmax_sh[1]), fmaxf(wmax_sh[2], wmax_sh[3]));
                atomicMax(&gmax[h], f2key(m2));
            }
        }
    }
}

// ---------------------------------------------------------------- K3: kp finalize
__global__ void kfin_kernel(float* __restrict__ kb, const unsigned* __restrict__ gmax) {
    int idx = blockIdx.x * 256 + threadIdx.x;  // exactly 7,680,000
    int h = (idx >> 6) & 3;
    float mx = key2f(gmax[h]);
    kb[idx] = 0.125f * (__expf(kb[idx] - mx) + 1e-6f);
}

// ---------------------------------------------------------------- K4: kvs partials
// grid (ncs, 3, 4); whole-chunk gumbel weights staged in LDS once; 16-row tiles.
__global__ __launch_bounds__(256) void kvs_kernel(
    const float* __restrict__ kb, const float* __restrict__ vb,
    const float* __restrict__ gum,
    float* __restrict__ kvsp, float* __restrict__ ksp, float* __restrict__ ksump,
    int chunk) {
    __shared__ __align__(16) float k_sh[16 * 64];
    __shared__ __align__(16) float v_sh[16 * 64];
    __shared__ float w_sh[2][944];
    const int c = blockIdx.x, kg = blockIdx.y, h = blockIdx.z;
    const int k0 = kg * 2;
    const int t = threadIdx.x;
    const int lane = t & 63;   // m
    const int wv = t >> 6;     // d-block
    const int n0 = c * chunk;
    const int n1 = (n0 + chunk < NN) ? (n0 + chunk) : NN;
    const int lenp = (chunk + 15) & ~15;
    for (int i = t; i < lenp; i += 256) {
        int n = n0 + i;
        bool val = (n < n1);
        w_sh[0][i] = val ? __expf(gum[n * 24 + h * KK + k0] * 4.0f) : 0.f;
        w_sh[1][i] = val ? __expf(gum[n * 24 + h * KK + k0 + 1] * 4.0f) : 0.f;
    }
    float acc[2][16];
    #pragma unroll
    for (int kk = 0; kk < 2; ++kk)
        #pragma unroll
        for (int i = 0; i < 16; ++i) acc[kk][i] = 0.f;
    float ks_acc[2] = {0.f, 0.f};
    float ksum_acc = 0.f;
    const float4* kb4 = (const float4*)kb;
    const float4* vb4 = (const float4*)vb;
    for (int nt = n0; nt < n1; nt += 16) {
        __syncthreads();
        #pragma unroll
        for (int q = 0; q < 2; ++q) {
            int idx4 = t + q * 256;       // 512 float4 = 16 rows x 32
            int row = idx4 >> 5;
            int wi = idx4 & 31;
            int n = nt + row;
            float4 val = make_float4(0.f, 0.f, 0.f, 0.f);
            if (n < n1)
                val = (wi < 16) ? kb4[n * 64 + h * 16 + wi]
                                : vb4[n * 64 + h * 16 + (wi - 16)];
            if (wi < 16) *(float4*)&k_sh[row * 64 + wi * 4] = val;
            else         *(float4*)&v_sh[row * 64 + (wi - 16) * 4] = val;
        }
        __syncthreads();
        const int bw = nt - n0;
        #pragma unroll
        for (int j = 0; j < 16; ++j) {
            float kpm = k_sh[j * 64 + lane];
            ksum_acc += kpm;
            float a0 = kpm * w_sh[0][bw + j];
            float a1 = kpm * w_sh[1][bw + j];
            ks_acc[0] += a0; ks_acc[1] += a1;
            const float4* v4 = (const float4*)&v_sh[j * 64 + wv * 16];
            float4 vv0 = v4[0], vv1 = v4[1], vv2 = v4[2], vv3 = v4[3];
            acc[0][ 0] += a0 * vv0.x; acc[0][ 1] += a0 * vv0.y;
            acc[0][ 2] += a0 * vv0.z; acc[0][ 3] += a0 * vv0.w;
            acc[0][ 4] += a0 * vv1.x; acc[0][ 5] += a0 * vv1.y;
            acc[0][ 6] += a0 * vv1.z; acc[0][ 7] += a0 * vv1.w;
            acc[0][ 8] += a0 * vv2.x; acc[0][ 9] += a0 * vv2.y;
            acc[0][10] += a0 * vv2.z; acc[0][11] += a0 * vv2.w;
            acc[0][12] += a0 * vv3.x; acc[0][13] += a0 * vv3.y;
            acc[0][14] += a0 * vv3.z; acc[0][15] += a0 * vv3.w;
            acc[1][ 0] += a1 * vv0.x; acc[1][ 1] += a1 * vv0.y;
            acc[1][ 2] += a1 * vv0.z; acc[1][ 3] += a1 * vv0.w;
            acc[1][ 4] += a1 * vv1.x; acc[1][ 5] += a1 * vv1.y;
            acc[1][ 6] += a1 * vv1.z; acc[1][ 7] += a1 * vv1.w;
            acc[1][ 8] += a1 * vv2.x; acc[1][ 9] += a1 * vv2.y;
            acc[1][10] += a1 * vv2.z; acc[1][11] += a1 * vv2.w;
            acc[1][12] += a1 * vv3.x; acc[1][13] += a1 * vv3.y;
            acc[1][14] += a1 * vv3.z; acc[1][15] += a1 * vv3.w;
        }
    }
    #pragma unroll
    for (int kk = 0; kk < 2; ++kk) {
        int base = (((c * HH + h) * KK + k0 + kk) * 64 + lane) * 64 + wv * 16;
        float4* o4 = (float4*)&kvsp[base];
        o4[0] = make_float4(acc[kk][0], acc[kk][1], acc[kk][2], acc[kk][3]);
        o4[1] = make_float4(acc[kk][4], acc[kk][5], acc[kk][6], acc[kk][7]);
        o4[2] = make_float4(acc[kk][8], acc[kk][9], acc[kk][10], acc[kk][11]);
        o4[3] = make_float4(acc[kk][12], acc[kk][13], acc[kk][14], acc[kk][15]);
    }
    if (wv == 0) {
        ksp[((c * HH + h) * KK + k0 + 0) * 64 + lane] = ks_acc[0];
        ksp[((c * HH + h) * KK + k0 + 1) * 64 + lane] = ks_acc[1];
        if (kg == 0) ksump[(c * HH + h) * 64 + lane] = ksum_acc;
    }
}

// ---------------------------------------------------------------- K5: reduce partials
__global__ void reduce_kernel(const float* __restrict__ kvsp, const float* __restrict__ ksp,
                              const float* __restrict__ ksump,
                              float* __restrict__ kvs, float* __restrict__ kss,
                              float* __restrict__ ksum, int ncs) {
    int idx = blockIdx.x * 256 + threadIdx.x;
    if (idx < 98304) {
        float s = 0.f;
        for (int c = 0; c < ncs; ++c) s += kvsp[c * 98304 + idx];
        kvs[idx] = s;
    } else if (idx < 98304 + 1536) {
        int o = idx - 98304;
        float s = 0.f;
        for (int c = 0; c < ncs; ++c) s += ksp[c * 1536 + o];
        kss[o] = s;
    } else if (idx < 98304 + 1536 + 256) {
        int o = idx - 98304 - 1536;
        float s = 0.f;
        for (int c = 0; c < ncs; ++c) s += ksump[c * 256 + o];
        ksum[o] = s;
    }
}

// ---------------------------------------------------------------- K6: z_num/z_den -> z_out, norm
__global__ __launch_bounds__(256) void znum_kernel(
    const float* __restrict__ qb, const float* __restrict__ kvs,
    const float* __restrict__ kss, const float* __restrict__ ksum,
    float* __restrict__ zout, float* __restrict__ nrm) {
    __shared__ __align__(16) float smem[13312];
    float* kvs_sh  = smem;          // 4096 (phase 2)
    float* ks_sh   = smem;          // 384  (phase 1 only)
    float* ksum_sh = smem + 384;    // 64   (phase 1 only)
    float* qpT     = smem + 4096;   // 8448
    float* zdi     = smem + 12544;  // 768
    const int t = threadIdx.x;
    const int tile = blockIdx.x, h = blockIdx.y;
    const int n0 = tile * 128;
    for (int i = t; i < 384; i += 256) ks_sh[i] = kss[h * 384 + i];
    if (t < 64) ksum_sh[t] = ksum[h * 64 + t];
    #pragma unroll
    for (int q = 0; q < 32; ++q) {
        int idx = t + q * 256;
        int nn2 = idx >> 6, m = idx & 63;
        int n = n0 + nn2;
        qpT[m * 132 + nn2] = (n < NN) ? qb[n * NHD + h * DD + m] : 0.f;
    }
    __syncthreads();
    #pragma unroll
    for (int p = 0; p < 4; ++p) {
        int idx = t + p * 256;
        if (idx < 768) {
            int node = idx / 6, k = idx % 6;
            float s = 0.f;
            for (int m = 0; m < 64; ++m) s += qpT[m * 132 + node] * ks_sh[k * 64 + m];
            zdi[idx] = 1.0f / s;
        } else if (idx < 896) {
            int node = idx - 768;
            float s = 0.f;
            for (int m = 0; m < 64; ++m) s += qpT[m * 132 + node] * ksum_sh[m];
            int n = n0 + node;
            if (n < NN) nrm[n * HH + h] = s;
        }
    }
    __syncthreads();
    const int tc = t & 15, tr = t >> 4;
    float out[8][4];
    #pragma unroll
    for (int i = 0; i < 8; ++i) { out[i][0] = 0.f; out[i][1] = 0.f; out[i][2] = 0.f; out[i][3] = 0.f; }
    for (int k = 0; k < KK; ++k) {
        const float* src = kvs + h * 24576 + k * 4096;
        #pragma unroll
        for (int q = 0; q < 16; ++q) kvs_sh[t + q * 256] = src[t + q * 256];
        __syncthreads();
        float s[8][4];
        #pragma unroll
        for (int i = 0; i < 8; ++i) { s[i][0] = 0.f; s[i][1] = 0.f; s[i][2] = 0.f; s[i][3] = 0.f; }
        const float* kbase = kvs_sh + tc * 4;
        #pragma unroll 4
        for (int m = 0; m < 64; ++m) {
            float4 b = *(const float4*)(kbase + m * 64);
            float a[8];
            *(float4*)&a[0] = *(const float4*)&qpT[m * 132 + tr * 8];
            *(float4*)&a[4] = *(const float4*)&qpT[m * 132 + tr * 8 + 4];
            #pragma unroll
            for (int i = 0; i < 8; ++i) {
                s[i][0] += a[i] * b.x;
                s[i][1] += a[i] * b.y;
                s[i][2] += a[i] * b.z;
                s[i][3] += a[i] * b.w;
            }
        }
        #pragma unroll
        for (int i = 0; i < 8; ++i) {
            float zv = zdi[(tr * 8 + i) * 6 + k];
            out[i][0] += s[i][0] * zv;
            out[i][1] += s[i][1] * zv;
            out[i][2] += s[i][2] * zv;
            out[i][3] += s[i][3] * zv;
        }
        __syncthreads();
    }
    const float inv6 = 1.0f / 6.0f;
    #pragma unroll
    for (int i = 0; i < 8; ++i) {
        int n = n0 + tr * 8 + i;
        if (n < NN) {
            float4 o = make_float4(out[i][0] * inv6, out[i][1] * inv6,
                                   out[i][2] * inv6, out[i][3] * inv6);
            *(float4*)&zout[n * NHD + h * DD + tc * 4] = o;
        }
    }
}

// ---------------------------------------------------------------- K7: output projection (f32 out)
__global__ __launch_bounds__(256) void outproj_kernel(
    const float* __restrict__ zout, const float* __restrict__ Wo,
    const float* __restrict__ bo, float* __restrict__ out) {
    __shared__ float zsh[16][NHD];
    const int t = threadIdx.x;
    const int n0 = blockIdx.x * 16;
    #pragma unroll
    for (int q = 0; q < 16; ++q) {
        int idx = t + q * 256;
        int nn2 = idx >> 8, r = idx & 255;
        zsh[nn2][r] = zout[(n0 + nn2) * NHD + r];
    }
    __syncthreads();
    const int c = t & 63, g = t >> 6;
    float acc[4];
    #pragma unroll
    for (int i = 0; i < 4; ++i) acc[i] = bo[c];
    for (int r = 0; r < 256; ++r) {
        float w = Wo[r * 64 + c];
        #pragma unroll
        for (int i = 0; i < 4; ++i) acc[i] += zsh[g + 4 * i][r] * w;
    }
    #pragma unroll
    for (int i = 0; i < 4; ++i)
        out[(n0 + g + 4 * i) * 64 + c] = acc[i];
}

// ---------------------------------------------------------------- K8: edges (f32 out)
__global__ __launch_bounds__(256) void edge_kernel(
    const float* __restrict__ qb, const float* __restrict__ kb,
    const int* __restrict__ ei, const float* __restrict__ nrm,
    float* __restrict__ out) {
    const int t = threadIdx.x;
    const int lane = t & 63, w = t >> 6;
    const int e = blockIdx.x * 4 + w;
    const int s = ei[e], d = ei[EE + e];
    float4 qv = *(const float4*)&qb[d * NHD + lane * 4];
    float4 kv = *(const float4*)&kb[s * NHD + lane * 4];
    float p = qv.x * kv.x + qv.y * kv.y + qv.z * kv.z + qv.w * kv.w;
    #pragma unroll
    for (int off = 1; off < 16; off <<= 1) p += __shfl_xor(p, off, 64);
    if ((lane & 15) == 0) {
        int h = lane >> 4;
        out[ZOFF + e * 4 + h] = p / nrm[d * HH + h];
    }
}

// ---------------------------------------------------------------- launch
extern "C" void kernel_launch(void* const* d_in, const int* in_sizes, int n_in,
                              void* d_out, int out_size, void* d_ws, size_t ws_size,
                              hipStream_t stream) {
    (void)in_sizes; (void)n_in; (void)out_size;
    const float* z  = (const float*)d_in[0];
    const float* Wq = (const float*)d_in[1];
    const float* bq = (const float*)d_in[2];
    const float* Wk = (const float*)d_in[3];
    const float* bk = (const float*)d_in[4];
    const float* Wv = (const float*)d_in[5];
    const float* bv = (const float*)d_in[6];
    const float* Wo = (const float*)d_in[7];
    const float* bo = (const float*)d_in[8];
    const float* proj = (const float*)d_in[9];
    const float* gum  = (const float*)d_in[10];
    const int*   ei   = (const int*)d_in[11];
    float* out = (float*)d_out;
    float* ws = (float*)d_ws;

    // chunk count: prefer 64 (6 blocks/CU in kvs); fall back to the proven 32 layout.
    int ncs = 64;
    if (ws_size < (size_t)(23260100 + (size_t)64 * 100096) * 4) ncs = 32;
    const size_t need = (size_t)(23260100 + (size_t)ncs * 100096) * 4;  // 1536+256+98304 per chunk
    if (ws_size < need) return;
    const int chunk = (NN + ncs - 1) / ncs;   // 469 or 938

    float* qb    = ws;                  // 7,680,000
    float* kb    = ws + 7680000;        // 7,680,000
    float* vb    = ws + 15360000;       // 7,680,000 (reused as zout after kvs)
    float* zout  = vb;
    float* kvs   = ws + 23040000;       // 98,304
    float* kss   = ws + 23138304;       // 1,536
    float* ksum  = ws + 23139840;       // 256
    float* nrm   = ws + 23140096;       // 120,000
    unsigned* gmax = (unsigned*)(ws + 23260096);  // 4
    float* ksp   = ws + 23260100;               // ncs*1536
    float* ksump = ksp + (size_t)ncs * 1536;    // ncs*256
    float* kvsp  = ksump + (size_t)ncs * 256;   // ncs*98304

    init_kernel<<<1, 64, 0, stream>>>(gmax);
    qkv_kernel<<<938, 256, 0, stream>>>(z, Wq, bq, Wk, bk, Wv, bv, qb, kb, vb);
    feat_kernel<<<dim3(469, HH), 256, 0, stream>>>(qb, kb, proj, gmax);
    kfin_kernel<<<30000, 256, 0, stream>>>(kb, gmax);
    kvs_kernel<<<dim3(ncs, 3, HH), 256, 0, stream>>>(kb, vb, gum, kvsp, ksp, ksump, chunk);
    reduce_kernel<<<392, 256, 0, stream>>>(kvsp, ksp, ksump, kvs, kss, ksum, ncs);
    znum_kernel<<<dim3(235, HH), 256, 0, stream>>>(qb, kvs, kss, ksum, zout, nrm);
    outproj_kernel<<<1875, 256, 0, stream>>>(zout, Wo, bo, out);
    edge_kernel<<<120000, 256, 0, stream>>>(qb, kb, ei, nrm, out);
}

// Round 6
// 520.024 us; speedup vs baseline: 2.1370x; 1.2261x over previous
//
#include <hip/hip_runtime.h>
#include <hip/hip_bf16.h>

#define NN   30000
#define DIN  128
#define NHD  256      // H*D
#define HH   4
#define DD   64
#define MM   64
#define KK   6
#define EE   480000
#define ZOFF 1920000  // 30000*64

__device__ __forceinline__ unsigned f2key(float f) {
    unsigned u = __float_as_uint(f);
    return (u & 0x80000000u) ? ~u : (u | 0x80000000u);
}
__device__ __forceinline__ float key2f(unsigned k) {
    return __uint_as_float((k & 0x80000000u) ? (k ^ 0x80000000u) : ~k);
}

// ---------------------------------------------------------------- init
__global__ void init_kernel(unsigned* gmax) {
    if (threadIdx.x < HH) gmax[threadIdx.x] = 0u;
}

// ---------------------------------------------------------------- K1: qkv GEMM
// 64-node tile, 4 nodes x 16 cols per thread. Conflict-free layouts:
//   zsh padded [64][132] (132%32==4 -> 4 node-rows in distinct banks)
//   wsh read at dword-stride 4 (cols g*64+tx*4) -> 2-way only.
__device__ __forceinline__ void gemm_one(const float* __restrict__ W,
                                         const float* __restrict__ b,
                                         float* __restrict__ O, float sc,
                                         const float (*zsh)[132], float* wsh,
                                         int t, int n0) {
    const int tx = t & 15, ty = t >> 4;
    float4 acc[4][4];
    #pragma unroll
    for (int i = 0; i < 4; ++i)
        #pragma unroll
        for (int g = 0; g < 4; ++g) acc[i][g] = make_float4(0.f, 0.f, 0.f, 0.f);
    const float4* W4 = (const float4*)W;
    for (int rt = 0; rt < 4; ++rt) {
        __syncthreads();
        #pragma unroll
        for (int q = 0; q < 8; ++q) {
            int idx4 = t + q * 256;            // 2048 float4 = 32 rows x 64
            *(float4*)&wsh[idx4 * 4] = W4[rt * 2048 + idx4];
        }
        __syncthreads();
        #pragma unroll 4
        for (int j = 0; j < 32; ++j) {
            const int col = rt * 32 + j;
            float a0 = zsh[ty][col];
            float a1 = zsh[ty + 16][col];
            float a2 = zsh[ty + 32][col];
            float a3 = zsh[ty + 48][col];
            #pragma unroll
            for (int g = 0; g < 4; ++g) {
                float4 bb = *(const float4*)&wsh[j * 256 + g * 64 + tx * 4];
                acc[0][g].x += a0 * bb.x; acc[0][g].y += a0 * bb.y;
                acc[0][g].z += a0 * bb.z; acc[0][g].w += a0 * bb.w;
                acc[1][g].x += a1 * bb.x; acc[1][g].y += a1 * bb.y;
                acc[1][g].z += a1 * bb.z; acc[1][g].w += a1 * bb.w;
                acc[2][g].x += a2 * bb.x; acc[2][g].y += a2 * bb.y;
                acc[2][g].z += a2 * bb.z; acc[2][g].w += a2 * bb.w;
                acc[3][g].x += a3 * bb.x; acc[3][g].y += a3 * bb.y;
                acc[3][g].z += a3 * bb.z; acc[3][g].w += a3 * bb.w;
            }
        }
    }
    #pragma unroll
    for (int g = 0; g < 4; ++g) {
        float4 bias = *(const float4*)&b[g * 64 + tx * 4];
        #pragma unroll
        for (int i = 0; i < 4; ++i) {
            int n = n0 + ty + i * 16;
            if (n < NN) {
                float4 o;
                o.x = (acc[i][g].x + bias.x) * sc;
                o.y = (acc[i][g].y + bias.y) * sc;
                o.z = (acc[i][g].z + bias.z) * sc;
                o.w = (acc[i][g].w + bias.w) * sc;
                *(float4*)&O[(size_t)n * NHD + g * 64 + tx * 4] = o;
            }
        }
    }
}

__global__ __launch_bounds__(256) void qkv_kernel(
    const float* __restrict__ z,
    const float* __restrict__ Wq, const float* __restrict__ bq,
    const float* __restrict__ Wk, const float* __restrict__ bk,
    const float* __restrict__ Wv, const float* __restrict__ bv,
    float* __restrict__ qb, float* __restrict__ kb, float* __restrict__ vb) {
    __shared__ __align__(16) float zsh[64][132];
    __shared__ __align__(16) float wsh[32 * 256];
    const int t = threadIdx.x;
    const int n0 = blockIdx.x * 64;
    const float4* z4 = (const float4*)z;
    #pragma unroll
    for (int q = 0; q < 8; ++q) {
        int idx4 = t + q * 256;                // 2048 float4 = 64 rows x 32
        int row = idx4 >> 5, c4 = idx4 & 31;
        float4 v = make_float4(0.f, 0.f, 0.f, 0.f);
        if (n0 + row < NN) v = z4[(size_t)(n0 + row) * 32 + c4];
        *(float4*)&zsh[row][c4 * 4] = v;
    }
    gemm_one(Wq, bq, qb, 2.0f, zsh, wsh, t, n0);
    gemm_one(Wk, bk, kb, 2.0f, zsh, wsh, t, n0);
    gemm_one(Wv, bv, vb, 1.0f, zsh, wsh, t, n0);
}

// ---------------------------------------------------------------- K2: random features (GEMM form)
__global__ __launch_bounds__(256) void feat_kernel(
    float* __restrict__ qb, float* __restrict__ kb,
    const float* __restrict__ proj, unsigned* __restrict__ gmax) {
    __shared__ __align__(16) float pT[64][68];   // pT[d][m]
    __shared__ __align__(16) float tT[64][68];   // tT[d][n]
    __shared__ float diag_sh[64];
    __shared__ float wmax_sh[4];
    const int t = threadIdx.x;
    const int h = blockIdx.y;
    const int n0 = blockIdx.x * 64;
    const int tx = t & 15, ty = t >> 4;
    const float dn = 0.35355339059327373f;  // 64^-0.25
    const float4* proj4 = (const float4*)proj;
    #pragma unroll
    for (int q = 0; q < 4; ++q) {
        int idx4 = t + q * 256;
        int m = idx4 >> 4, d4 = idx4 & 15;
        float4 v = proj4[m * 16 + d4];
        pT[d4 * 4 + 0][m] = v.x; pT[d4 * 4 + 1][m] = v.y;
        pT[d4 * 4 + 2][m] = v.z; pT[d4 * 4 + 3][m] = v.w;
    }
    #pragma unroll
    for (int pass = 0; pass < 2; ++pass) {
        float* buf = pass ? kb : qb;
        const float4* b4 = (const float4*)buf;
        __syncthreads();
        #pragma unroll
        for (int q = 0; q < 4; ++q) {
            int idx4 = t + q * 256;
            int n = idx4 >> 4, d4 = idx4 & 15;
            float4 v = make_float4(0.f, 0.f, 0.f, 0.f);
            if (n0 + n < NN) v = b4[(n0 + n) * 64 + h * 16 + d4];
            tT[d4 * 4 + 0][n] = v.x * dn; tT[d4 * 4 + 1][n] = v.y * dn;
            tT[d4 * 4 + 2][n] = v.z * dn; tT[d4 * 4 + 3][n] = v.w * dn;
        }
        __syncthreads();
        if (t < 64) {
            float s = 0.f;
            #pragma unroll 8
            for (int d = 0; d < 64; ++d) { float v = tT[d][t]; s += v * v; }
            diag_sh[t] = 0.5f * s;
        }
        __syncthreads();
        float acc[4][4];
        #pragma unroll
        for (int i = 0; i < 4; ++i)
            #pragma unroll
            for (int j = 0; j < 4; ++j) acc[i][j] = 0.f;
        #pragma unroll 8
        for (int d = 0; d < 64; ++d) {
            float4 a = *(const float4*)&tT[d][ty * 4];
            float4 b = *(const float4*)&pT[d][tx * 4];
            float a_[4] = {a.x, a.y, a.z, a.w};
            float b_[4] = {b.x, b.y, b.z, b.w};
            #pragma unroll
            for (int i = 0; i < 4; ++i)
                #pragma unroll
                for (int j = 0; j < 4; ++j) acc[i][j] += a_[i] * b_[j];
        }
        if (pass == 0) {
            #pragma unroll
            for (int i = 0; i < 4; ++i) {
                int n = n0 + ty * 4 + i;
                float mx = fmaxf(fmaxf(acc[i][0], acc[i][1]), fmaxf(acc[i][2], acc[i][3]));
                mx = fmaxf(mx, __shfl_xor(mx, 1, 64));
                mx = fmaxf(mx, __shfl_xor(mx, 2, 64));
                mx = fmaxf(mx, __shfl_xor(mx, 4, 64));
                mx = fmaxf(mx, __shfl_xor(mx, 8, 64));
                if (n < NN) {
                    float dg = diag_sh[ty * 4 + i] + mx;
                    float4 o;
                    o.x = 0.125f * (__expf(acc[i][0] - dg) + 1e-6f);
                    o.y = 0.125f * (__expf(acc[i][1] - dg) + 1e-6f);
                    o.z = 0.125f * (__expf(acc[i][2] - dg) + 1e-6f);
                    o.w = 0.125f * (__expf(acc[i][3] - dg) + 1e-6f);
                    *(float4*)&qb[n * NHD + h * DD + tx * 4] = o;
                }
            }
        } else {
            float km = -3.4e38f;
            #pragma unroll
            for (int i = 0; i < 4; ++i) {
                int n = n0 + ty * 4 + i;
                if (n < NN) {
                    float dg = diag_sh[ty * 4 + i];
                    float4 o;
                    o.x = acc[i][0] - dg; o.y = acc[i][1] - dg;
                    o.z = acc[i][2] - dg; o.w = acc[i][3] - dg;
                    *(float4*)&kb[n * NHD + h * DD + tx * 4] = o;
                    km = fmaxf(km, fmaxf(fmaxf(acc[i][0], acc[i][1]),
                                         fmaxf(acc[i][2], acc[i][3])));
                }
            }
            #pragma unroll
            for (int off = 1; off < 64; off <<= 1) km = fmaxf(km, __shfl_xor(km, off, 64));
            if ((t & 63) == 0) wmax_sh[t >> 6] = km;
            __syncthreads();
            if (t == 0) {
                float m2 = fmaxf(fmaxf(wmax_sh[0], wmax_sh[1]), fmaxf(wmax_sh[2], wmax_sh[3]));
                atomicMax(&gmax[h], f2key(m2));
            }
        }
    }
}

// ---------------------------------------------------------------- K3: kp finalize
__global__ void kfin_kernel(float* __restrict__ kb, const unsigned* __restrict__ gmax) {
    int idx = blockIdx.x * 256 + threadIdx.x;  // exactly 7,680,000
    int h = (idx >> 6) & 3;
    float mx = key2f(gmax[h]);
    kb[idx] = 0.125f * (__expf(kb[idx] - mx) + 1e-6f);
}

// ---------------------------------------------------------------- K4: kvs partials
__global__ __launch_bounds__(256) void kvs_kernel(
    const float* __restrict__ kb, const float* __restrict__ vb,
    const float* __restrict__ gum,
    float* __restrict__ kvsp, float* __restrict__ ksp, float* __restrict__ ksump,
    int chunk) {
    __shared__ __align__(16) float k_sh[16 * 64];
    __shared__ __align__(16) float v_sh[16 * 64];
    __shared__ float w_sh[2][944];
    const int c = blockIdx.x, kg = blockIdx.y, h = blockIdx.z;
    const int k0 = kg * 2;
    const int t = threadIdx.x;
    const int lane = t & 63;   // m
    const int wv = t >> 6;     // d-block
    const int n0 = c * chunk;
    const int n1 = (n0 + chunk < NN) ? (n0 + chunk) : NN;
    const int lenp = (chunk + 15) & ~15;
    for (int i = t; i < lenp; i += 256) {
        int n = n0 + i;
        bool val = (n < n1);
        w_sh[0][i] = val ? __expf(gum[n * 24 + h * KK + k0] * 4.0f) : 0.f;
        w_sh[1][i] = val ? __expf(gum[n * 24 + h * KK + k0 + 1] * 4.0f) : 0.f;
    }
    float acc[2][16];
    #pragma unroll
    for (int kk = 0; kk < 2; ++kk)
        #pragma unroll
        for (int i = 0; i < 16; ++i) acc[kk][i] = 0.f;
    float ks_acc[2] = {0.f, 0.f};
    float ksum_acc = 0.f;
    const float4* kb4 = (const float4*)kb;
    const float4* vb4 = (const float4*)vb;
    for (int nt = n0; nt < n1; nt += 16) {
        __syncthreads();
        #pragma unroll
        for (int q = 0; q < 2; ++q) {
            int idx4 = t + q * 256;       // 512 float4 = 16 rows x 32
            int row = idx4 >> 5;
            int wi = idx4 & 31;
            int n = nt + row;
            float4 val = make_float4(0.f, 0.f, 0.f, 0.f);
            if (n < n1)
                val = (wi < 16) ? kb4[n * 64 + h * 16 + wi]
                                : vb4[n * 64 + h * 16 + (wi - 16)];
            if (wi < 16) *(float4*)&k_sh[row * 64 + wi * 4] = val;
            else         *(float4*)&v_sh[row * 64 + (wi - 16) * 4] = val;
        }
        __syncthreads();
        const int bw = nt - n0;
        #pragma unroll
        for (int j = 0; j < 16; ++j) {
            float kpm = k_sh[j * 64 + lane];
            ksum_acc += kpm;
            float a0 = kpm * w_sh[0][bw + j];
            float a1 = kpm * w_sh[1][bw + j];
            ks_acc[0] += a0; ks_acc[1] += a1;
            const float4* v4 = (const float4*)&v_sh[j * 64 + wv * 16];
            float4 vv0 = v4[0], vv1 = v4[1], vv2 = v4[2], vv3 = v4[3];
            acc[0][ 0] += a0 * vv0.x; acc[0][ 1] += a0 * vv0.y;
            acc[0][ 2] += a0 * vv0.z; acc[0][ 3] += a0 * vv0.w;
            acc[0][ 4] += a0 * vv1.x; acc[0][ 5] += a0 * vv1.y;
            acc[0][ 6] += a0 * vv1.z; acc[0][ 7] += a0 * vv1.w;
            acc[0][ 8] += a0 * vv2.x; acc[0][ 9] += a0 * vv2.y;
            acc[0][10] += a0 * vv2.z; acc[0][11] += a0 * vv2.w;
            acc[0][12] += a0 * vv3.x; acc[0][13] += a0 * vv3.y;
            acc[0][14] += a0 * vv3.z; acc[0][15] += a0 * vv3.w;
            acc[1][ 0] += a1 * vv0.x; acc[1][ 1] += a1 * vv0.y;
            acc[1][ 2] += a1 * vv0.z; acc[1][ 3] += a1 * vv0.w;
            acc[1][ 4] += a1 * vv1.x; acc[1][ 5] += a1 * vv1.y;
            acc[1][ 6] += a1 * vv1.z; acc[1][ 7] += a1 * vv1.w;
            acc[1][ 8] += a1 * vv2.x; acc[1][ 9] += a1 * vv2.y;
            acc[1][10] += a1 * vv2.z; acc[1][11] += a1 * vv2.w;
            acc[1][12] += a1 * vv3.x; acc[1][13] += a1 * vv3.y;
            acc[1][14] += a1 * vv3.z; acc[1][15] += a1 * vv3.w;
        }
    }
    #pragma unroll
    for (int kk = 0; kk < 2; ++kk) {
        int base = (((c * HH + h) * KK + k0 + kk) * 64 + lane) * 64 + wv * 16;
        float4* o4 = (float4*)&kvsp[base];
        o4[0] = make_float4(acc[kk][0], acc[kk][1], acc[kk][2], acc[kk][3]);
        o4[1] = make_float4(acc[kk][4], acc[kk][5], acc[kk][6], acc[kk][7]);
        o4[2] = make_float4(acc[kk][8], acc[kk][9], acc[kk][10], acc[kk][11]);
        o4[3] = make_float4(acc[kk][12], acc[kk][13], acc[kk][14], acc[kk][15]);
    }
    if (wv == 0) {
        ksp[((c * HH + h) * KK + k0 + 0) * 64 + lane] = ks_acc[0];
        ksp[((c * HH + h) * KK + k0 + 1) * 64 + lane] = ks_acc[1];
        if (kg == 0) ksump[(c * HH + h) * 64 + lane] = ksum_acc;
    }
}

// ---------------------------------------------------------------- K5: reduce partials
__global__ void reduce_kernel(const float* __restrict__ kvsp, const float* __restrict__ ksp,
                              const float* __restrict__ ksump,
                              float* __restrict__ kvs, float* __restrict__ kss,
                              float* __restrict__ ksum, int ncs) {
    int idx = blockIdx.x * 256 + threadIdx.x;
    if (idx < 98304) {
        float s = 0.f;
        for (int c = 0; c < ncs; ++c) s += kvsp[c * 98304 + idx];
        kvs[idx] = s;
    } else if (idx < 98304 + 1536) {
        int o = idx - 98304;
        float s = 0.f;
        for (int c = 0; c < ncs; ++c) s += ksp[c * 1536 + o];
        kss[o] = s;
    } else if (idx < 98304 + 1536 + 256) {
        int o = idx - 98304 - 1536;
        float s = 0.f;
        for (int c = 0; c < ncs; ++c) s += ksump[c * 256 + o];
        ksum[o] = s;
    }
}

// ---------------------------------------------------------------- K6: z_num/z_den -> z_out, norm
__global__ __launch_bounds__(256) void znum_kernel(
    const float* __restrict__ qb, const float* __restrict__ kvs,
    const float* __restrict__ kss, const float* __restrict__ ksum,
    float* __restrict__ zout, float* __restrict__ nrm) {
    __shared__ __align__(16) float smem[13312];
    float* kvs_sh  = smem;          // 4096 (phase 2)
    float* ks_sh   = smem;          // 384  (phase 1 only)
    float* ksum_sh = smem + 384;    // 64   (phase 1 only)
    float* qpT     = smem + 4096;   // 8448
    float* zdi     = smem + 12544;  // 768
    const int t = threadIdx.x;
    const int tile = blockIdx.x, h = blockIdx.y;
    const int n0 = tile * 128;
    for (int i = t; i < 384; i += 256) ks_sh[i] = kss[h * 384 + i];
    if (t < 64) ksum_sh[t] = ksum[h * 64 + t];
    #pragma unroll
    for (int q = 0; q < 32; ++q) {
        int idx = t + q * 256;
        int nn2 = idx >> 6, m = idx & 63;
        int n = n0 + nn2;
        qpT[m * 132 + nn2] = (n < NN) ? qb[n * NHD + h * DD + m] : 0.f;
    }
    __syncthreads();
    #pragma unroll
    for (int p = 0; p < 4; ++p) {
        int idx = t + p * 256;
        if (idx < 768) {
            int node = idx / 6, k = idx % 6;
            float s = 0.f;
            for (int m = 0; m < 64; ++m) s += qpT[m * 132 + node] * ks_sh[k * 64 + m];
            zdi[idx] = 1.0f / s;
        } else if (idx < 896) {
            int node = idx - 768;
            float s = 0.f;
            for (int m = 0; m < 64; ++m) s += qpT[m * 132 + node] * ksum_sh[m];
            int n = n0 + node;
            if (n < NN) nrm[n * HH + h] = s;
        }
    }
    __syncthreads();
    const int tc = t & 15, tr = t >> 4;
    float out[8][4];
    #pragma unroll
    for (int i = 0; i < 8; ++i) { out[i][0] = 0.f; out[i][1] = 0.f; out[i][2] = 0.f; out[i][3] = 0.f; }
    for (int k = 0; k < KK; ++k) {
        const float* src = kvs + h * 24576 + k * 4096;
        #pragma unroll
        for (int q = 0; q < 16; ++q) kvs_sh[t + q * 256] = src[t + q * 256];
        __syncthreads();
        float s[8][4];
        #pragma unroll
        for (int i = 0; i < 8; ++i) { s[i][0] = 0.f; s[i][1] = 0.f; s[i][2] = 0.f; s[i][3] = 0.f; }
        const float* kbase = kvs_sh + tc * 4;
        #pragma unroll 4
        for (int m = 0; m < 64; ++m) {
            float4 b = *(const float4*)(kbase + m * 64);
            float a[8];
            *(float4*)&a[0] = *(const float4*)&qpT[m * 132 + tr * 8];
            *(float4*)&a[4] = *(const float4*)&qpT[m * 132 + tr * 8 + 4];
            #pragma unroll
            for (int i = 0; i < 8; ++i) {
                s[i][0] += a[i] * b.x;
                s[i][1] += a[i] * b.y;
                s[i][2] += a[i] * b.z;
                s[i][3] += a[i] * b.w;
            }
        }
        #pragma unroll
        for (int i = 0; i < 8; ++i) {
            float zv = zdi[(tr * 8 + i) * 6 + k];
            out[i][0] += s[i][0] * zv;
            out[i][1] += s[i][1] * zv;
            out[i][2] += s[i][2] * zv;
            out[i][3] += s[i][3] * zv;
        }
        __syncthreads();
    }
    const float inv6 = 1.0f / 6.0f;
    #pragma unroll
    for (int i = 0; i < 8; ++i) {
        int n = n0 + tr * 8 + i;
        if (n < NN) {
            float4 o = make_float4(out[i][0] * inv6, out[i][1] * inv6,
                                   out[i][2] * inv6, out[i][3] * inv6);
            *(float4*)&zout[n * NHD + h * DD + tc * 4] = o;
        }
    }
}

// ---------------------------------------------------------------- K7: output projection (f32 out)
__global__ __launch_bounds__(256) void outproj_kernel(
    const float* __restrict__ zout, const float* __restrict__ Wo,
    const float* __restrict__ bo, float* __restrict__ out) {
    __shared__ float zsh[16][NHD];
    const int t = threadIdx.x;
    const int n0 = blockIdx.x * 16;
    #pragma unroll
    for (int q = 0; q < 16; ++q) {
        int idx = t + q * 256;
        int nn2 = idx >> 8, r = idx & 255;
        zsh[nn2][r] = zout[(n0 + nn2) * NHD + r];
    }
    __syncthreads();
    const int c = t & 63, g = t >> 6;
    float acc[4];
    #pragma unroll
    for (int i = 0; i < 4; ++i) acc[i] = bo[c];
    for (int r = 0; r < 256; ++r) {
        float w = Wo[r * 64 + c];
        #pragma unroll
        for (int i = 0; i < 4; ++i) acc[i] += zsh[g + 4 * i][r] * w;
    }
    #pragma unroll
    for (int i = 0; i < 4; ++i)
        out[(n0 + g + 4 * i) * 64 + c] = acc[i];
}

// ---------------------------------------------------------------- K8: edges (f32 out)
__global__ __launch_bounds__(256) void edge_kernel(
    const float* __restrict__ qb, const float* __restrict__ kb,
    const int* __restrict__ ei, const float* __restrict__ nrm,
    float* __restrict__ out) {
    const int t = threadIdx.x;
    const int lane = t & 63, w = t >> 6;
    const int e = blockIdx.x * 4 + w;
    const int s = ei[e], d = ei[EE + e];
    float4 qv = *(const float4*)&qb[d * NHD + lane * 4];
    float4 kv = *(const float4*)&kb[s * NHD + lane * 4];
    float p = qv.x * kv.x + qv.y * kv.y + qv.z * kv.z + qv.w * kv.w;
    #pragma unroll
    for (int off = 1; off < 16; off <<= 1) p += __shfl_xor(p, off, 64);
    if ((lane & 15) == 0) {
        int h = lane >> 4;
        out[ZOFF + e * 4 + h] = p / nrm[d * HH + h];
    }
}

// ---------------------------------------------------------------- launch
extern "C" void kernel_launch(void* const* d_in, const int* in_sizes, int n_in,
                              void* d_out, int out_size, void* d_ws, size_t ws_size,
                              hipStream_t stream) {
    (void)in_sizes; (void)n_in; (void)out_size;
    const float* z  = (const float*)d_in[0];
    const float* Wq = (const float*)d_in[1];
    const float* bq = (const float*)d_in[2];
    const float* Wk = (const float*)d_in[3];
    const float* bk = (const float*)d_in[4];
    const float* Wv = (const float*)d_in[5];
    const float* bv = (const float*)d_in[6];
    const float* Wo = (const float*)d_in[7];
    const float* bo = (const float*)d_in[8];
    const float* proj = (const float*)d_in[9];
    const float* gum  = (const float*)d_in[10];
    const int*   ei   = (const int*)d_in[11];
    float* out = (float*)d_out;
    float* ws = (float*)d_ws;

    // chunk count: prefer 64 (6 blocks/CU in kvs); fall back to the proven 32 layout.
    int ncs = 64;
    if (ws_size < (size_t)(23260100 + (size_t)64 * 100096) * 4) ncs = 32;
    const size_t need = (size_t)(23260100 + (size_t)ncs * 100096) * 4;
    if (ws_size < need) return;
    const int chunk = (NN + ncs - 1) / ncs;   // 469 or 938

    float* qb    = ws;                  // 7,680,000
    float* kb    = ws + 7680000;        // 7,680,000
    float* vb    = ws + 15360000;       // 7,680,000 (reused as zout after kvs)
    float* zout  = vb;
    float* kvs   = ws + 23040000;       // 98,304
    float* kss   = ws + 23138304;       // 1,536
    float* ksum  = ws + 23139840;       // 256
    float* nrm   = ws + 23140096;       // 120,000
    unsigned* gmax = (unsigned*)(ws + 23260096);  // 4
    float* ksp   = ws + 23260100;               // ncs*1536
    float* ksump = ksp + (size_t)ncs * 1536;    // ncs*256
    float* kvsp  = ksump + (size_t)ncs * 256;   // ncs*98304

    init_kernel<<<1, 64, 0, stream>>>(gmax);
    qkv_kernel<<<469, 256, 0, stream>>>(z, Wq, bq, Wk, bk, Wv, bv, qb, kb, vb);
    feat_kernel<<<dim3(469, HH), 256, 0, stream>>>(qb, kb, proj, gmax);
    kfin_kernel<<<30000, 256, 0, stream>>>(kb, gmax);
    kvs_kernel<<<dim3(ncs, 3, HH), 256, 0, stream>>>(kb, vb, gum, kvsp, ksp, ksump, chunk);
    reduce_kernel<<<392, 256, 0, stream>>>(kvsp, ksp, ksump, kvs, kss, ksum, ncs);
    znum_kernel<<<dim3(235, HH), 256, 0, stream>>>(qb, kvs, kss, ksum, zout, nrm);
    outproj_kernel<<<1875, 256, 0, stream>>>(zout, Wo, bo, out);
    edge_kernel<<<120000, 256, 0, stream>>>(qb, kb, ei, nrm, out);
}

// Round 7
// 464.038 us; speedup vs baseline: 2.3948x; 1.1206x over previous
//
#include <hip/hip_runtime.h>
#include <hip/hip_bf16.h>

#define NN   30000
#define DIN  128
#define NHD  256      // H*D
#define HH   4
#define DD   64
#define MM   64
#define KK   6
#define EE   480000
#define ZOFF 1920000  // 30000*64

__device__ __forceinline__ unsigned f2key(float f) {
    unsigned u = __float_as_uint(f);
    return (u & 0x80000000u) ? ~u : (u | 0x80000000u);
}
__device__ __forceinline__ float key2f(unsigned k) {
    return __uint_as_float((k & 0x80000000u) ? (k ^ 0x80000000u) : ~k);
}
__device__ __forceinline__ unsigned short f2bf(float f) {   // RNE
    unsigned u = __float_as_uint(f);
    unsigned r = ((u >> 16) & 1u) + 0x7fffu;
    return (unsigned short)((u + r) >> 16);
}

// ---------------------------------------------------------------- init
__global__ void init_kernel(unsigned* gmax) {
    if (threadIdx.x < HH) gmax[threadIdx.x] = 0u;
}

// ---------------------------------------------------------------- K1: qkv GEMM
__device__ __forceinline__ void gemm_one(const float* __restrict__ W,
                                         const float* __restrict__ b,
                                         float* __restrict__ O, float sc,
                                         const float (*zsh)[132], float* wsh,
                                         int t, int n0) {
    const int tx = t & 15, ty = t >> 4;
    float4 acc[4][4];
    #pragma unroll
    for (int i = 0; i < 4; ++i)
        #pragma unroll
        for (int g = 0; g < 4; ++g) acc[i][g] = make_float4(0.f, 0.f, 0.f, 0.f);
    const float4* W4 = (const float4*)W;
    for (int rt = 0; rt < 4; ++rt) {
        __syncthreads();
        #pragma unroll
        for (int q = 0; q < 8; ++q) {
            int idx4 = t + q * 256;            // 2048 float4 = 32 rows x 64
            *(float4*)&wsh[idx4 * 4] = W4[rt * 2048 + idx4];
        }
        __syncthreads();
        #pragma unroll 4
        for (int j = 0; j < 32; ++j) {
            const int col = rt * 32 + j;
            float a0 = zsh[ty][col];
            float a1 = zsh[ty + 16][col];
            float a2 = zsh[ty + 32][col];
            float a3 = zsh[ty + 48][col];
            #pragma unroll
            for (int g = 0; g < 4; ++g) {
                float4 bb = *(const float4*)&wsh[j * 256 + g * 64 + tx * 4];
                acc[0][g].x += a0 * bb.x; acc[0][g].y += a0 * bb.y;
                acc[0][g].z += a0 * bb.z; acc[0][g].w += a0 * bb.w;
                acc[1][g].x += a1 * bb.x; acc[1][g].y += a1 * bb.y;
                acc[1][g].z += a1 * bb.z; acc[1][g].w += a1 * bb.w;
                acc[2][g].x += a2 * bb.x; acc[2][g].y += a2 * bb.y;
                acc[2][g].z += a2 * bb.z; acc[2][g].w += a2 * bb.w;
                acc[3][g].x += a3 * bb.x; acc[3][g].y += a3 * bb.y;
                acc[3][g].z += a3 * bb.z; acc[3][g].w += a3 * bb.w;
            }
        }
    }
    #pragma unroll
    for (int g = 0; g < 4; ++g) {
        float4 bias = *(const float4*)&b[g * 64 + tx * 4];
        #pragma unroll
        for (int i = 0; i < 4; ++i) {
            int n = n0 + ty + i * 16;
            if (n < NN) {
                float4 o;
                o.x = (acc[i][g].x + bias.x) * sc;
                o.y = (acc[i][g].y + bias.y) * sc;
                o.z = (acc[i][g].z + bias.z) * sc;
                o.w = (acc[i][g].w + bias.w) * sc;
                *(float4*)&O[(size_t)n * NHD + g * 64 + tx * 4] = o;
            }
        }
    }
}

__global__ __launch_bounds__(256) void qkv_kernel(
    const float* __restrict__ z,
    const float* __restrict__ Wq, const float* __restrict__ bq,
    const float* __restrict__ Wk, const float* __restrict__ bk,
    const float* __restrict__ Wv, const float* __restrict__ bv,
    float* __restrict__ qb, float* __restrict__ kb, float* __restrict__ vb) {
    __shared__ __align__(16) float zsh[64][132];
    __shared__ __align__(16) float wsh[32 * 256];
    const int t = threadIdx.x;
    const int n0 = blockIdx.x * 64;
    const float4* z4 = (const float4*)z;
    #pragma unroll
    for (int q = 0; q < 8; ++q) {
        int idx4 = t + q * 256;                // 2048 float4 = 64 rows x 32
        int row = idx4 >> 5, c4 = idx4 & 31;
        float4 v = make_float4(0.f, 0.f, 0.f, 0.f);
        if (n0 + row < NN) v = z4[(size_t)(n0 + row) * 32 + c4];
        *(float4*)&zsh[row][c4 * 4] = v;
    }
    gemm_one(Wq, bq, qb, 2.0f, zsh, wsh, t, n0);
    gemm_one(Wk, bk, kb, 2.0f, zsh, wsh, t, n0);
    gemm_one(Wv, bv, vb, 1.0f, zsh, wsh, t, n0);
}

// ---------------------------------------------------------------- K2: random features (GEMM form)
__global__ __launch_bounds__(256) void feat_kernel(
    float* __restrict__ qb, float* __restrict__ kb,
    const float* __restrict__ proj, unsigned* __restrict__ gmax,
    unsigned short* __restrict__ qbh) {
    __shared__ __align__(16) float pT[64][68];   // pT[d][m]
    __shared__ __align__(16) float tT[64][68];   // tT[d][n]
    __shared__ float diag_sh[64];
    __shared__ float wmax_sh[4];
    const int t = threadIdx.x;
    const int h = blockIdx.y;
    const int n0 = blockIdx.x * 64;
    const int tx = t & 15, ty = t >> 4;
    const float dn = 0.35355339059327373f;  // 64^-0.25
    const float4* proj4 = (const float4*)proj;
    #pragma unroll
    for (int q = 0; q < 4; ++q) {
        int idx4 = t + q * 256;
        int m = idx4 >> 4, d4 = idx4 & 15;
        float4 v = proj4[m * 16 + d4];
        pT[d4 * 4 + 0][m] = v.x; pT[d4 * 4 + 1][m] = v.y;
        pT[d4 * 4 + 2][m] = v.z; pT[d4 * 4 + 3][m] = v.w;
    }
    #pragma unroll
    for (int pass = 0; pass < 2; ++pass) {
        float* buf = pass ? kb : qb;
        const float4* b4 = (const float4*)buf;
        __syncthreads();
        #pragma unroll
        for (int q = 0; q < 4; ++q) {
            int idx4 = t + q * 256;
            int n = idx4 >> 4, d4 = idx4 & 15;
            float4 v = make_float4(0.f, 0.f, 0.f, 0.f);
            if (n0 + n < NN) v = b4[(n0 + n) * 64 + h * 16 + d4];
            tT[d4 * 4 + 0][n] = v.x * dn; tT[d4 * 4 + 1][n] = v.y * dn;
            tT[d4 * 4 + 2][n] = v.z * dn; tT[d4 * 4 + 3][n] = v.w * dn;
        }
        __syncthreads();
        if (t < 64) {
            float s = 0.f;
            #pragma unroll 8
            for (int d = 0; d < 64; ++d) { float v = tT[d][t]; s += v * v; }
            diag_sh[t] = 0.5f * s;
        }
        __syncthreads();
        float acc[4][4];
        #pragma unroll
        for (int i = 0; i < 4; ++i)
            #pragma unroll
            for (int j = 0; j < 4; ++j) acc[i][j] = 0.f;
        #pragma unroll 8
        for (int d = 0; d < 64; ++d) {
            float4 a = *(const float4*)&tT[d][ty * 4];
            float4 b = *(const float4*)&pT[d][tx * 4];
            float a_[4] = {a.x, a.y, a.z, a.w};
            float b_[4] = {b.x, b.y, b.z, b.w};
            #pragma unroll
            for (int i = 0; i < 4; ++i)
                #pragma unroll
                for (int j = 0; j < 4; ++j) acc[i][j] += a_[i] * b_[j];
        }
        if (pass == 0) {
            #pragma unroll
            for (int i = 0; i < 4; ++i) {
                int n = n0 + ty * 4 + i;
                float mx = fmaxf(fmaxf(acc[i][0], acc[i][1]), fmaxf(acc[i][2], acc[i][3]));
                mx = fmaxf(mx, __shfl_xor(mx, 1, 64));
                mx = fmaxf(mx, __shfl_xor(mx, 2, 64));
                mx = fmaxf(mx, __shfl_xor(mx, 4, 64));
                mx = fmaxf(mx, __shfl_xor(mx, 8, 64));
                if (n < NN) {
                    float dg = diag_sh[ty * 4 + i] + mx;
                    float4 o;
                    o.x = 0.125f * (__expf(acc[i][0] - dg) + 1e-6f);
                    o.y = 0.125f * (__expf(acc[i][1] - dg) + 1e-6f);
                    o.z = 0.125f * (__expf(acc[i][2] - dg) + 1e-6f);
                    o.w = 0.125f * (__expf(acc[i][3] - dg) + 1e-6f);
                    *(float4*)&qb[n * NHD + h * DD + tx * 4] = o;
                    if (qbh) {
                        ushort4 u;
                        u.x = f2bf(o.x); u.y = f2bf(o.y);
                        u.z = f2bf(o.z); u.w = f2bf(o.w);
                        *(ushort4*)&qbh[n * NHD + h * DD + tx * 4] = u;
                    }
                }
            }
        } else {
            float km = -3.4e38f;
            #pragma unroll
            for (int i = 0; i < 4; ++i) {
                int n = n0 + ty * 4 + i;
                if (n < NN) {
                    float dg = diag_sh[ty * 4 + i];
                    float4 o;
                    o.x = acc[i][0] - dg; o.y = acc[i][1] - dg;
                    o.z = acc[i][2] - dg; o.w = acc[i][3] - dg;
                    *(float4*)&kb[n * NHD + h * DD + tx * 4] = o;
                    km = fmaxf(km, fmaxf(fmaxf(acc[i][0], acc[i][1]),
                                         fmaxf(acc[i][2], acc[i][3])));
                }
            }
            #pragma unroll
            for (int off = 1; off < 64; off <<= 1) km = fmaxf(km, __shfl_xor(km, off, 64));
            if ((t & 63) == 0) wmax_sh[t >> 6] = km;
            __syncthreads();
            if (t == 0) {
                float m2 = fmaxf(fmaxf(wmax_sh[0], wmax_sh[1]), fmaxf(wmax_sh[2], wmax_sh[3]));
                atomicMax(&gmax[h], f2key(m2));
            }
        }
    }
}

// ---------------------------------------------------------------- K3: kp finalize (float4 + bf16 mirror)
__global__ void kfin_kernel(float* __restrict__ kb, const unsigned* __restrict__ gmax,
                            unsigned short* __restrict__ kbh) {
    int idx = (blockIdx.x * 256 + threadIdx.x) * 4;   // 7,680,000 total elems
    int h = (idx >> 6) & 3;
    float mx = key2f(gmax[h]);
    float4 v = *(float4*)&kb[idx];
    v.x = 0.125f * (__expf(v.x - mx) + 1e-6f);
    v.y = 0.125f * (__expf(v.y - mx) + 1e-6f);
    v.z = 0.125f * (__expf(v.z - mx) + 1e-6f);
    v.w = 0.125f * (__expf(v.w - mx) + 1e-6f);
    *(float4*)&kb[idx] = v;
    if (kbh) {
        ushort4 u;
        u.x = f2bf(v.x); u.y = f2bf(v.y); u.z = f2bf(v.z); u.w = f2bf(v.w);
        *(ushort4*)&kbh[idx] = u;
    }
}

// ---------------------------------------------------------------- K4: kvs partials
__global__ __launch_bounds__(256) void kvs_kernel(
    const float* __restrict__ kb, const float* __restrict__ vb,
    const float* __restrict__ gum,
    float* __restrict__ kvsp, float* __restrict__ ksp, float* __restrict__ ksump,
    int chunk) {
    __shared__ __align__(16) float k_sh[16 * 64];
    __shared__ __align__(16) float v_sh[16 * 64];
    __shared__ float w_sh[2][944];
    const int c = blockIdx.x, kg = blockIdx.y, h = blockIdx.z;
    const int k0 = kg * 2;
    const int t = threadIdx.x;
    const int lane = t & 63;   // m
    const int wv = t >> 6;     // d-block
    const int n0 = c * chunk;
    const int n1 = (n0 + chunk < NN) ? (n0 + chunk) : NN;
    const int lenp = (chunk + 15) & ~15;
    for (int i = t; i < lenp; i += 256) {
        int n = n0 + i;
        bool val = (n < n1);
        w_sh[0][i] = val ? __expf(gum[n * 24 + h * KK + k0] * 4.0f) : 0.f;
        w_sh[1][i] = val ? __expf(gum[n * 24 + h * KK + k0 + 1] * 4.0f) : 0.f;
    }
    float acc[2][16];
    #pragma unroll
    for (int kk = 0; kk < 2; ++kk)
        #pragma unroll
        for (int i = 0; i < 16; ++i) acc[kk][i] = 0.f;
    float ks_acc[2] = {0.f, 0.f};
    float ksum_acc = 0.f;
    const float4* kb4 = (const float4*)kb;
    const float4* vb4 = (const float4*)vb;
    for (int nt = n0; nt < n1; nt += 16) {
        __syncthreads();
        #pragma unroll
        for (int q = 0; q < 2; ++q) {
            int idx4 = t + q * 256;       // 512 float4 = 16 rows x 32
            int row = idx4 >> 5;
            int wi = idx4 & 31;
            int n = nt + row;
            float4 val = make_float4(0.f, 0.f, 0.f, 0.f);
            if (n < n1)
                val = (wi < 16) ? kb4[n * 64 + h * 16 + wi]
                                : vb4[n * 64 + h * 16 + (wi - 16)];
            if (wi < 16) *(float4*)&k_sh[row * 64 + wi * 4] = val;
            else         *(float4*)&v_sh[row * 64 + (wi - 16) * 4] = val;
        }
        __syncthreads();
        const int bw = nt - n0;
        #pragma unroll
        for (int j = 0; j < 16; ++j) {
            float kpm = k_sh[j * 64 + lane];
            ksum_acc += kpm;
            float a0 = kpm * w_sh[0][bw + j];
            float a1 = kpm * w_sh[1][bw + j];
            ks_acc[0] += a0; ks_acc[1] += a1;
            const float4* v4 = (const float4*)&v_sh[j * 64 + wv * 16];
            float4 vv0 = v4[0], vv1 = v4[1], vv2 = v4[2], vv3 = v4[3];
            acc[0][ 0] += a0 * vv0.x; acc[0][ 1] += a0 * vv0.y;
            acc[0][ 2] += a0 * vv0.z; acc[0][ 3] += a0 * vv0.w;
            acc[0][ 4] += a0 * vv1.x; acc[0][ 5] += a0 * vv1.y;
            acc[0][ 6] += a0 * vv1.z; acc[0][ 7] += a0 * vv1.w;
            acc[0][ 8] += a0 * vv2.x; acc[0][ 9] += a0 * vv2.y;
            acc[0][10] += a0 * vv2.z; acc[0][11] += a0 * vv2.w;
            acc[0][12] += a0 * vv3.x; acc[0][13] += a0 * vv3.y;
            acc[0][14] += a0 * vv3.z; acc[0][15] += a0 * vv3.w;
            acc[1][ 0] += a1 * vv0.x; acc[1][ 1] += a1 * vv0.y;
            acc[1][ 2] += a1 * vv0.z; acc[1][ 3] += a1 * vv0.w;
            acc[1][ 4] += a1 * vv1.x; acc[1][ 5] += a1 * vv1.y;
            acc[1][ 6] += a1 * vv1.z; acc[1][ 7] += a1 * vv1.w;
            acc[1][ 8] += a1 * vv2.x; acc[1][ 9] += a1 * vv2.y;
            acc[1][10] += a1 * vv2.z; acc[1][11] += a1 * vv2.w;
            acc[1][12] += a1 * vv3.x; acc[1][13] += a1 * vv3.y;
            acc[1][14] += a1 * vv3.z; acc[1][15] += a1 * vv3.w;
        }
    }
    #pragma unroll
    for (int kk = 0; kk < 2; ++kk) {
        int base = (((c * HH + h) * KK + k0 + kk) * 64 + lane) * 64 + wv * 16;
        float4* o4 = (float4*)&kvsp[base];
        o4[0] = make_float4(acc[kk][0], acc[kk][1], acc[kk][2], acc[kk][3]);
        o4[1] = make_float4(acc[kk][4], acc[kk][5], acc[kk][6], acc[kk][7]);
        o4[2] = make_float4(acc[kk][8], acc[kk][9], acc[kk][10], acc[kk][11]);
        o4[3] = make_float4(acc[kk][12], acc[kk][13], acc[kk][14], acc[kk][15]);
    }
    if (wv == 0) {
        ksp[((c * HH + h) * KK + k0 + 0) * 64 + lane] = ks_acc[0];
        ksp[((c * HH + h) * KK + k0 + 1) * 64 + lane] = ks_acc[1];
        if (kg == 0) ksump[(c * HH + h) * 64 + lane] = ksum_acc;
    }
}

// ---------------------------------------------------------------- K5: reduce partials
__global__ void reduce_kernel(const float* __restrict__ kvsp, const float* __restrict__ ksp,
                              const float* __restrict__ ksump,
                              float* __restrict__ kvs, float* __restrict__ kss,
                              float* __restrict__ ksum, int ncs) {
    int idx = blockIdx.x * 256 + threadIdx.x;
    if (idx < 98304) {
        float s = 0.f;
        for (int c = 0; c < ncs; ++c) s += kvsp[c * 98304 + idx];
        kvs[idx] = s;
    } else if (idx < 98304 + 1536) {
        int o = idx - 98304;
        float s = 0.f;
        for (int c = 0; c < ncs; ++c) s += ksp[c * 1536 + o];
        kss[o] = s;
    } else if (idx < 98304 + 1536 + 256) {
        int o = idx - 98304 - 1536;
        float s = 0.f;
        for (int c = 0; c < ncs; ++c) s += ksump[c * 256 + o];
        ksum[o] = s;
    }
}

// ---------------------------------------------------------------- K6: z_num/z_den -> z_out, norm
__global__ __launch_bounds__(256) void znum_kernel(
    const float* __restrict__ qb, const float* __restrict__ kvs,
    const float* __restrict__ kss, const float* __restrict__ ksum,
    float* __restrict__ zout, float* __restrict__ nrm) {
    __shared__ __align__(16) float smem[13312];
    float* kvs_sh  = smem;          // 4096 (phase 2)
    float* ks_sh   = smem;          // 384  (phase 1 only)
    float* ksum_sh = smem + 384;    // 64   (phase 1 only)
    float* qpT     = smem + 4096;   // 8448
    float* zdi     = smem + 12544;  // 768
    const int t = threadIdx.x;
    const int tile = blockIdx.x, h = blockIdx.y;
    const int n0 = tile * 128;
    for (int i = t; i < 384; i += 256) ks_sh[i] = kss[h * 384 + i];
    if (t < 64) ksum_sh[t] = ksum[h * 64 + t];
    #pragma unroll
    for (int q = 0; q < 32; ++q) {
        int idx = t + q * 256;
        int nn2 = idx >> 6, m = idx & 63;
        int n = n0 + nn2;
        qpT[m * 132 + nn2] = (n < NN) ? qb[n * NHD + h * DD + m] : 0.f;
    }
    __syncthreads();
    #pragma unroll
    for (int p = 0; p < 4; ++p) {
        int idx = t + p * 256;
        if (idx < 768) {
            int node = idx / 6, k = idx % 6;
            float s = 0.f;
            for (int m = 0; m < 64; ++m) s += qpT[m * 132 + node] * ks_sh[k * 64 + m];
            zdi[idx] = 1.0f / s;
        } else if (idx < 896) {
            int node = idx - 768;
            float s = 0.f;
            for (int m = 0; m < 64; ++m) s += qpT[m * 132 + node] * ksum_sh[m];
            int n = n0 + node;
            if (n < NN) nrm[n * HH + h] = s;
        }
    }
    __syncthreads();
    const int tc = t & 15, tr = t >> 4;
    float out[8][4];
    #pragma unroll
    for (int i = 0; i < 8; ++i) { out[i][0] = 0.f; out[i][1] = 0.f; out[i][2] = 0.f; out[i][3] = 0.f; }
    for (int k = 0; k < KK; ++k) {
        const float* src = kvs + h * 24576 + k * 4096;
        #pragma unroll
        for (int q = 0; q < 16; ++q) kvs_sh[t + q * 256] = src[t + q * 256];
        __syncthreads();
        float s[8][4];
        #pragma unroll
        for (int i = 0; i < 8; ++i) { s[i][0] = 0.f; s[i][1] = 0.f; s[i][2] = 0.f; s[i][3] = 0.f; }
        const float* kbase = kvs_sh + tc * 4;
        #pragma unroll 4
        for (int m = 0; m < 64; ++m) {
            float4 b = *(const float4*)(kbase + m * 64);
            float a[8];
            *(float4*)&a[0] = *(const float4*)&qpT[m * 132 + tr * 8];
            *(float4*)&a[4] = *(const float4*)&qpT[m * 132 + tr * 8 + 4];
            #pragma unroll
            for (int i = 0; i < 8; ++i) {
                s[i][0] += a[i] * b.x;
                s[i][1] += a[i] * b.y;
                s[i][2] += a[i] * b.z;
                s[i][3] += a[i] * b.w;
            }
        }
        #pragma unroll
        for (int i = 0; i < 8; ++i) {
            float zv = zdi[(tr * 8 + i) * 6 + k];
            out[i][0] += s[i][0] * zv;
            out[i][1] += s[i][1] * zv;
            out[i][2] += s[i][2] * zv;
            out[i][3] += s[i][3] * zv;
        }
        __syncthreads();
    }
    const float inv6 = 1.0f / 6.0f;
    #pragma unroll
    for (int i = 0; i < 8; ++i) {
        int n = n0 + tr * 8 + i;
        if (n < NN) {
            float4 o = make_float4(out[i][0] * inv6, out[i][1] * inv6,
                                   out[i][2] * inv6, out[i][3] * inv6);
            *(float4*)&zout[n * NHD + h * DD + tc * 4] = o;
        }
    }
}

// ---------------------------------------------------------------- K7: output projection (f32 out)
__global__ __launch_bounds__(256) void outproj_kernel(
    const float* __restrict__ zout, const float* __restrict__ Wo,
    const float* __restrict__ bo, float* __restrict__ out) {
    __shared__ float zsh[16][NHD];
    const int t = threadIdx.x;
    const int n0 = blockIdx.x * 16;
    #pragma unroll
    for (int q = 0; q < 16; ++q) {
        int idx = t + q * 256;
        int nn2 = idx >> 8, r = idx & 255;
        zsh[nn2][r] = zout[(n0 + nn2) * NHD + r];
    }
    __syncthreads();
    const int c = t & 63, g = t >> 6;
    float acc[4];
    #pragma unroll
    for (int i = 0; i < 4; ++i) acc[i] = bo[c];
    for (int r = 0; r < 256; ++r) {
        float w = Wo[r * 64 + c];
        #pragma unroll
        for (int i = 0; i < 4; ++i) acc[i] += zsh[g + 4 * i][r] * w;
    }
    #pragma unroll
    for (int i = 0; i < 4; ++i)
        out[(n0 + g + 4 * i) * 64 + c] = acc[i];
}

// ---------------------------------------------------------------- K8a: edges, bf16 gather (8 edges/block)
__global__ __launch_bounds__(256) void edge_bf16_kernel(
    const unsigned short* __restrict__ qbh, const unsigned short* __restrict__ kbh,
    const int* __restrict__ ei, const float* __restrict__ nrm,
    float* __restrict__ out) {
    const int t = threadIdx.x;
    const int lane5 = t & 31;
    const int e = blockIdx.x * 8 + (t >> 5);
    const int s = ei[e], d = ei[EE + e];
    const uint4* q4 = (const uint4*)qbh;
    const uint4* k4 = (const uint4*)kbh;
    uint4 qv = q4[d * 32 + lane5];
    uint4 kv = k4[s * 32 + lane5];
    const unsigned short* qs = (const unsigned short*)&qv;
    const unsigned short* ks = (const unsigned short*)&kv;
    float p = 0.f;
    #pragma unroll
    for (int i = 0; i < 8; ++i) {
        float qf = __uint_as_float((unsigned)qs[i] << 16);
        float kf = __uint_as_float((unsigned)ks[i] << 16);
        p += qf * kf;
    }
    p += __shfl_xor(p, 1, 64);
    p += __shfl_xor(p, 2, 64);
    p += __shfl_xor(p, 4, 64);
    if ((lane5 & 7) == 0) {
        int h = lane5 >> 3;
        out[ZOFF + e * 4 + h] = p / nrm[d * HH + h];
    }
}

// ---------------------------------------------------------------- K8b: edges, f32 fallback
__global__ __launch_bounds__(256) void edge_kernel(
    const float* __restrict__ qb, const float* __restrict__ kb,
    const int* __restrict__ ei, const float* __restrict__ nrm,
    float* __restrict__ out) {
    const int t = threadIdx.x;
    const int lane = t & 63, w = t >> 6;
    const int e = blockIdx.x * 4 + w;
    const int s = ei[e], d = ei[EE + e];
    float4 qv = *(const float4*)&qb[d * NHD + lane * 4];
    float4 kv = *(const float4*)&kb[s * NHD + lane * 4];
    float p = qv.x * kv.x + qv.y * kv.y + qv.z * kv.z + qv.w * kv.w;
    #pragma unroll
    for (int off = 1; off < 16; off <<= 1) p += __shfl_xor(p, off, 64);
    if ((lane & 15) == 0) {
        int h = lane >> 4;
        out[ZOFF + e * 4 + h] = p / nrm[d * HH + h];
    }
}

// ---------------------------------------------------------------- launch
extern "C" void kernel_launch(void* const* d_in, const int* in_sizes, int n_in,
                              void* d_out, int out_size, void* d_ws, size_t ws_size,
                              hipStream_t stream) {
    (void)in_sizes; (void)n_in; (void)out_size;
    const float* z  = (const float*)d_in[0];
    const float* Wq = (const float*)d_in[1];
    const float* bq = (const float*)d_in[2];
    const float* Wk = (const float*)d_in[3];
    const float* bk = (const float*)d_in[4];
    const float* Wv = (const float*)d_in[5];
    const float* bv = (const float*)d_in[6];
    const float* Wo = (const float*)d_in[7];
    const float* bo = (const float*)d_in[8];
    const float* proj = (const float*)d_in[9];
    const float* gum  = (const float*)d_in[10];
    const int*   ei   = (const int*)d_in[11];
    float* out = (float*)d_out;
    float* ws = (float*)d_ws;

    // Config ladder (float units): base=23,260,100; +bf16 mirrors 7,680,000; +ncs*100,096.
    const size_t fs = ws_size / 4;
    bool use_bf16; int ncs;
    if      (fs >= 37346244) { use_bf16 = true;  ncs = 64; }
    else if (fs >= 34143172) { use_bf16 = true;  ncs = 32; }
    else if (fs >= 29666244) { use_bf16 = false; ncs = 64; }
    else if (fs >= 27737028) { use_bf16 = false; ncs = 32; }
    else return;
    const int chunk = (NN + ncs - 1) / ncs;   // 469 or 938

    float* qb    = ws;                  // 7,680,000
    float* kb    = ws + 7680000;        // 7,680,000
    float* vb    = ws + 15360000;       // 7,680,000 (reused as zout after kvs)
    float* zout  = vb;
    float* kvs   = ws + 23040000;       // 98,304
    float* kss   = ws + 23138304;       // 1,536
    float* ksum  = ws + 23139840;       // 256
    float* nrm   = ws + 23140096;       // 120,000
    unsigned* gmax = (unsigned*)(ws + 23260096);  // 4
    float* p = ws + 23260100;
    unsigned short* qbh = nullptr;
    unsigned short* kbh = nullptr;
    if (use_bf16) {
        qbh = (unsigned short*)p;              // 7,680,000 bf16 = 3,840,000 fl
        kbh = (unsigned short*)(p + 3840000);  // 7,680,000 bf16
        p += 7680000;
    }
    float* ksp   = p;                           // ncs*1536
    float* ksump = ksp + (size_t)ncs * 1536;    // ncs*256
    float* kvsp  = ksump + (size_t)ncs * 256;   // ncs*98304

    init_kernel<<<1, 64, 0, stream>>>(gmax);
    qkv_kernel<<<469, 256, 0, stream>>>(z, Wq, bq, Wk, bk, Wv, bv, qb, kb, vb);
    feat_kernel<<<dim3(469, HH), 256, 0, stream>>>(qb, kb, proj, gmax, qbh);
    kfin_kernel<<<7500, 256, 0, stream>>>(kb, gmax, kbh);
    kvs_kernel<<<dim3(ncs, 3, HH), 256, 0, stream>>>(kb, vb, gum, kvsp, ksp, ksump, chunk);
    reduce_kernel<<<392, 256, 0, stream>>>(kvsp, ksp, ksump, kvs, kss, ksum, ncs);
    znum_kernel<<<dim3(235, HH), 256, 0, stream>>>(qb, kvs, kss, ksum, zout, nrm);
    outproj_kernel<<<1875, 256, 0, stream>>>(zout, Wo, bo, out);
    if (use_bf16) {
        edge_bf16_kernel<<<60000, 256, 0, stream>>>(qbh, kbh, ei, nrm, out);
    } else {
        edge_kernel<<<120000, 256, 0, stream>>>(qb, kb, ei, nrm, out);
    }
}